// Round 3
// baseline (1441.051 us; speedup 1.0000x reference)
//
#include <hip/hip_runtime.h>
#include <math.h>

// Problem constants (fixed by reference setup_inputs)
#define L0   4448   // flux length
#define L1P  278    // after conv1(stride4,pad7)->1112 then maxpool4
#define L2   139    // after conv2(stride2,pad3) on 278
#define NQ   8
#define NL   3
#define SD   256

#define H1S  292    // h1 row stride (words); 292%32=4 keeps writes spread

// CNOT-ring permutation (one layer of 8 CNOTs composed). Linear over GF(2):
// perm(x^m) = perm(x)^perm(m).
constexpr int permsrc_c(int x) {
    for (int q = 7; q >= 0; --q) {
        int cb = 7 - q, tb = 7 - ((q + 1) & 7);
        x ^= ((x >> cb) & 1) << tb;
    }
    return x;
}
constexpr int P40 = permsrc_c(0x40);
constexpr int P80 = permsrc_c(0x80);
constexpr int PC0 = permsrc_c(0xC0);

__device__ __forceinline__ int permsrc(int x) {
    #pragma unroll
    for (int q = 7; q >= 0; --q) {
        int cb = 7 - q, tb = 7 - ((q + 1) & 7);
        x ^= ((x >> cb) & 1) << tb;
    }
    return x;
}

// Combined 2-qubit (bits 7 and 6) gate: out = (U0 on bit7)(U1 on bit6) in.
// v[m7*2+m6] = input amp at index with bit7^=m7, bit6^=m6 (already permuted).
__device__ __forceinline__ void apply2(const float* __restrict__ U0,
                                       const float* __restrict__ U1,
                                       int a7, int a6,
                                       const float vr[4], const float vi[4],
                                       float& re, float& im)
{
    float nr = 0.0f, ni = 0.0f;
    #pragma unroll
    for (int m7 = 0; m7 < 2; ++m7) {
        const float ur0 = U0[(a7 * 2 + (a7 ^ m7)) * 2];
        const float ui0 = U0[(a7 * 2 + (a7 ^ m7)) * 2 + 1];
        #pragma unroll
        for (int m6 = 0; m6 < 2; ++m6) {
            const float ur1 = U1[(a6 * 2 + (a6 ^ m6)) * 2];
            const float ui1 = U1[(a6 * 2 + (a6 ^ m6)) * 2 + 1];
            const float cr = ur0 * ur1 - ui0 * ui1;
            const float ci = ur0 * ui1 + ui0 * ur1;
            const int   id = m7 * 2 + m6;
            nr += cr * vr[id] - ci * vi[id];
            ni += cr * vi[id] + ci * vr[id];
        }
    }
    re = nr; im = ni;
}

__global__ __launch_bounds__(256, 8)
void aec_fused_kernel(const float* __restrict__ flux,
                      const float* __restrict__ scalars,
                      const float* __restrict__ conv1_w,
                      const float* __restrict__ bn1_g, const float* __restrict__ bn1_b,
                      const float* __restrict__ conv2_w,
                      const float* __restrict__ bn2_g, const float* __restrict__ bn2_b,
                      const float* __restrict__ proj_w1, const float* __restrict__ proj_b1,
                      const float* __restrict__ proj_w2, const float* __restrict__ proj_b2,
                      const float* __restrict__ qw,
                      const float* __restrict__ head_w1, const float* __restrict__ head_b1,
                      const float* __restrict__ head_bn_g, const float* __restrict__ head_bn_b,
                      const float* __restrict__ head_w2, const float* __restrict__ head_b2,
                      float* __restrict__ out)
{
    const int b   = blockIdx.x;
    const int tid = threadIdx.x;

    // h1 [16][292]; dead after stage2, then aliased:
    //   s_hidden Bb[0..63], s_red Bb[64..95], s_q Bb[96..103], s_hid2 Bb[104..135],
    //   cre Bb[256..511], cim Bb[512..767]
    __shared__ __align__(16) float Bb[4676];
    // pool sums feat[32][8] during stage2; s_U[192] after proj1
    __shared__ __align__(16) float featU[256];

    float* s_hidden = Bb;
    float* s_red    = Bb + 64;
    float* s_q      = Bb + 96;
    float* s_hid2   = Bb + 104;
    float* s_cre    = Bb + 256;
    float* s_cim    = Bb + 512;
    float* s_U      = featU;

    const float BN_RSQ = 0.9999950000374997f;     // 1/sqrt(1+1e-5)

    // ---------------- stage 0: zero feat sums + h1 pads ----------------
    featU[tid] = 0.0f;
    if (tid < 160) {
        int ic = tid / 10, w = tid - ic * 10;
        int off = (w < 4) ? w : (278 + w);        // words {0..3} and {282..287}
        Bb[ic * H1S + off] = 0.0f;
    }

    // ---------------- stage 1: conv1 + bn + relu + maxpool4 -> h1 ----------------
    // 2 channels/thread: c2 = tid&7 -> {c2, c2+8}; window slot = tid>>3
    {
        const int c2   = tid & 7;
        const int slot = tid >> 3;
        const float* frow = flux + (size_t)b * L0;
        float wt0[15], wt1[15];
        #pragma unroll
        for (int k = 0; k < 15; ++k) {
            wt0[k] = conv1_w[c2 * 15 + k];
            wt1[k] = conv1_w[(c2 + 8) * 15 + k];
        }
        const float sc0 = bn1_g[c2] * BN_RSQ,     bt0 = bn1_b[c2];
        const float sc1 = bn1_g[c2 + 8] * BN_RSQ, bt1 = bn1_b[c2 + 8];

        for (int p = slot; p < L1P; p += 32) {
            // win[i] <-> flux idx x = 16p - 8 + i, i in [0,32); taps use i 1..27
            float win[32];
            if (p == 0) {
                #pragma unroll
                for (int i = 0; i < 8; ++i) win[i] = 0.0f;
                const float4* src = (const float4*)frow;
                #pragma unroll
                for (int v = 0; v < 6; ++v) {
                    float4 t4 = src[v];
                    win[8+4*v] = t4.x; win[9+4*v] = t4.y; win[10+4*v] = t4.z; win[11+4*v] = t4.w;
                }
            } else if (p == L1P - 1) {
                const float4* src = (const float4*)(frow + 16 * p - 8);
                #pragma unroll
                for (int v = 0; v < 6; ++v) {
                    float4 t4 = src[v];
                    win[4*v] = t4.x; win[1+4*v] = t4.y; win[2+4*v] = t4.z; win[3+4*v] = t4.w;
                }
                #pragma unroll
                for (int i = 24; i < 32; ++i) win[i] = 0.0f;
            } else {
                const float4* src = (const float4*)(frow + 16 * p - 8);
                #pragma unroll
                for (int v = 0; v < 8; ++v) {
                    float4 t4 = src[v];
                    win[4*v] = t4.x; win[1+4*v] = t4.y; win[2+4*v] = t4.z; win[3+4*v] = t4.w;
                }
            }
            float m0 = 0.0f, m1 = 0.0f;   // relu outputs >= 0
            #pragma unroll
            for (int j2 = 0; j2 < 4; ++j2) {
                float a0 = 0.0f, a1 = 0.0f;
                #pragma unroll
                for (int k = 0; k < 15; ++k) {
                    float wv = win[4*j2 + 1 + k];
                    a0 += wv * wt0[k];
                    a1 += wv * wt1[k];
                }
                m0 = fmaxf(m0, fmaxf(a0 * sc0 + bt0, 0.0f));
                m1 = fmaxf(m1, fmaxf(a1 * sc1 + bt1, 0.0f));
            }
            Bb[c2 * H1S + 4 + p]       = m0;
            Bb[(c2 + 8) * H1S + 4 + p] = m1;
        }
    }
    __syncthreads();

    // ---------------- stage 2: conv2 + bn + relu + fused adaptive pool ----------
    // 2 channels/thread: c2 = tid&15 -> {c2, c2+16}; g = tid>>4 -> even j0.
    // Pool bin b = [s_b, s_{b+1}] (inclusive overlap); a thread's <=10 positions
    // span at most 2 bins -> 2 register partials/channel, <=4 LDS atomicAdds.
    {
        const int c2 = tid & 15;
        const int g  = tid >> 4;
        const int j0   = (9 * g) & ~1;
        const int npos = ((g == 15) ? L2 : ((9 * (g + 1)) & ~1)) - j0;   // 8/10/5
        float acc0[10], acc1[10];
        #pragma unroll
        for (int r = 0; r < 10; ++r) { acc0[r] = 0.0f; acc1[r] = 0.0f; }

        #pragma unroll 1
        for (int t = 0; t < 8; ++t) {              // ic chunk of 2
            float wt0[14], wt1[14];
            const float2* w0 = (const float2*)(conv2_w + c2 * 112 + t * 14);
            const float2* w1 = (const float2*)(conv2_w + (c2 + 16) * 112 + t * 14);
            #pragma unroll
            for (int m = 0; m < 7; ++m) {
                float2 a2 = w0[m]; wt0[2*m] = a2.x; wt0[2*m+1] = a2.y;
                float2 b2 = w1[m]; wt1[2*m] = b2.x; wt1[2*m+1] = b2.y;
            }
            #pragma unroll
            for (int u = 0; u < 2; ++u) {
                const int ic = 2 * t + u;
                // win[i] <-> x = 2*j0 - 4 + i; tap (jj,k) -> i = 1 + 2*jj + k
                float win[28];
                const float4* src = (const float4*)(Bb + ic * H1S + 2 * j0);
                #pragma unroll
                for (int v = 0; v < 7; ++v) {
                    float4 t4 = src[v];
                    win[4*v] = t4.x; win[1+4*v] = t4.y; win[2+4*v] = t4.z; win[3+4*v] = t4.w;
                }
                #pragma unroll
                for (int jj = 0; jj < 10; ++jj) {
                    float s0 = 0.0f, s1 = 0.0f;
                    #pragma unroll
                    for (int k = 0; k < 7; ++k) {
                        float wv = win[1 + 2*jj + k];
                        s0 += wt0[u*7 + k] * wv;
                        s1 += wt1[u*7 + k] * wv;
                    }
                    acc0[jj] += s0;
                    acc1[jj] += s1;
                }
            }
        }
        const float sc0 = bn2_g[c2] * BN_RSQ,      bt0 = bn2_b[c2];
        const float sc1 = bn2_g[c2 + 16] * BN_RSQ, bt1 = bn2_b[c2 + 16];
        const int   b0  = (8 * j0) / 139;          // this thread's base bin
        const int   sB  = (139 * (b0 + 1)) >> 3;   // boundary: j<=sB -> b0, j>=sB -> b0+1
        const float rc0 = (b0 == 2 || b0 == 5) ? (1.0f/19.0f) : (1.0f/18.0f);
        const float rc1 = (b0 == 1 || b0 == 4) ? (1.0f/19.0f) : (1.0f/18.0f);
        float p00 = 0.f, p01 = 0.f, p10 = 0.f, p11 = 0.f;
        #pragma unroll
        for (int jj = 0; jj < 10; ++jj) {
            if (jj < npos) {
                const int j = j0 + jj;
                float v0 = fmaxf(acc0[jj] * sc0 + bt0, 0.0f);
                float v1 = fmaxf(acc1[jj] * sc1 + bt1, 0.0f);
                if (j <= sB) { p00 += v0; p10 += v1; }
                if (j >= sB) { p01 += v0; p11 += v1; }
            }
        }
        atomicAdd(&featU[c2 * 8 + b0],        p00 * rc0);
        atomicAdd(&featU[(c2 + 16) * 8 + b0], p10 * rc0);
        if (b0 < 7) {
            atomicAdd(&featU[c2 * 8 + b0 + 1],        p01 * rc1);
            atomicAdd(&featU[(c2 + 16) * 8 + b0 + 1], p11 * rc1);
        }
    }
    __syncthreads();

    // ---------------- proj1 (256 -> 64), relu ----------------
    {
        const int o = tid >> 2, s = tid & 3;
        const float4* wg = (const float4*)(proj_w1 + 64 * tid);   // == o*256 + s*64
        const float4* xf = (const float4*)(featU + 64 * s);
        float acc = 0.0f;
        #pragma unroll
        for (int t = 0; t < 16; ++t) {
            float4 w4 = wg[t], x4 = xf[t];
            acc += w4.x * x4.x + w4.y * x4.y + w4.z * x4.z + w4.w * x4.w;
        }
        acc += __shfl_down(acc, 2, 64);
        acc += __shfl_down(acc, 1, 64);
        if (s == 0) s_hidden[o] = fmaxf(acc + proj_b1[o], 0.0f);
    }
    __syncthreads();

    // gate matrices into featU (feat is dead); read after the proj2 barrier
    if (tid < NL * NQ) {
        float phi = qw[tid * 3 + 0], th = qw[tid * 3 + 1], om = qw[tid * 3 + 2];
        float ch = cosf(0.5f * th), sh = sinf(0.5f * th);
        float a  = 0.5f * (phi + om), bb = 0.5f * (phi - om);
        float ca = cosf(a), sa = sinf(a), cb = cosf(bb), sb = sinf(bb);
        float* U = &s_U[tid * 8];
        U[0] =  ca * ch; U[1] = -sa * ch;   // U00
        U[2] = -cb * sh; U[3] = -sb * sh;   // U01
        U[4] =  cb * sh; U[5] = -sb * sh;   // U10
        U[6] =  ca * ch; U[7] =  sa * ch;   // U11
    }

    // ---------------- proj2 (64 -> 256) + L2 normalize ----------------
    float re, im;
    {
        const float4* wg = (const float4*)(proj_w2 + 64 * tid);
        const float4* hf = (const float4*)s_hidden;
        float acc = proj_b2[tid];
        #pragma unroll
        for (int t = 0; t < 16; ++t) {
            float4 w4 = wg[t], x4 = hf[t];
            acc += w4.x * x4.x + w4.y * x4.y + w4.z * x4.z + w4.w * x4.w;
        }
        float ss = acc * acc;
        #pragma unroll
        for (int off = 32; off >= 1; off >>= 1) ss += __shfl_xor(ss, off, 64);
        if ((tid & 63) == 0) s_red[tid >> 6] = ss;
        __syncthreads();                           // also covers s_U writes
        float sst = s_red[0] + s_red[1] + s_red[2] + s_red[3];
        float n   = sqrtf(sst);
        float inv = 1.0f / fmaxf(n, 1e-12f);
        float xi  = acc * inv;
        if (n * inv < 1e-8f) xi = 0.0625f;        // uniform 1/sqrt(256)
        re = xi; im = 0.0f;
    }

    // ---------------- quantum circuit ----------------
    const int a7 = (tid >> 7) & 1, a6 = (tid >> 6) & 1;
    const int sP = permsrc(tid);

    // layer 0 combined gate on bits 7,6 (identity permutation before it)
    s_cre[tid] = re; s_cim[tid] = im;
    __syncthreads();
    {
        float vr[4], vi[4];
        vr[0] = re;                vi[0] = im;
        vr[1] = s_cre[tid ^ 0x40]; vi[1] = s_cim[tid ^ 0x40];
        vr[2] = s_cre[tid ^ 0x80]; vi[2] = s_cim[tid ^ 0x80];
        vr[3] = s_cre[tid ^ 0xC0]; vi[3] = s_cim[tid ^ 0xC0];
        __syncthreads();
        apply2(&s_U[0], &s_U[8], a7, a6, vr, vi, re, im);
    }

    #pragma unroll
    for (int l = 0; l < NL; ++l) {
        // gates q = 2..7 (bit positions 5..0): in-wave shuffles
        #pragma unroll
        for (int q = 2; q < NQ; ++q) {
            const float* U = &s_U[(l * NQ + q) * 8];
            const float u00r = U[0], u00i = U[1], u01r = U[2], u01i = U[3];
            const float u10r = U[4], u10i = U[5], u11r = U[6], u11i = U[7];
            const int bp = 7 - q;
            const float pre = __shfl_xor(re, 1 << bp, 64);
            const float pim = __shfl_xor(im, 1 << bp, 64);
            const int bit = (tid >> bp) & 1;
            const float csr = bit ? u11r : u00r;
            const float csi = bit ? u11i : u00i;
            const float cpr = bit ? u10r : u01r;
            const float cpi = bit ? u10i : u01i;
            const float nr = csr * re - csi * im + cpr * pre - cpi * pim;
            const float ni = csr * im + csi * re + cpr * pim + cpi * pre;
            re = nr; im = ni;
        }
        // CNOT-ring permutation, fused with next layer's combined (bit7,bit6) gate
        s_cre[tid] = re; s_cim[tid] = im;
        __syncthreads();
        if (l < NL - 1) {
            float vr[4], vi[4];
            vr[0] = s_cre[sP];       vi[0] = s_cim[sP];
            vr[1] = s_cre[sP ^ P40]; vi[1] = s_cim[sP ^ P40];
            vr[2] = s_cre[sP ^ P80]; vi[2] = s_cim[sP ^ P80];
            vr[3] = s_cre[sP ^ PC0]; vi[3] = s_cim[sP ^ PC0];
            __syncthreads();
            apply2(&s_U[((l + 1) * NQ + 0) * 8], &s_U[((l + 1) * NQ + 1) * 8],
                   a7, a6, vr, vi, re, im);
        } else {
            re = s_cre[sP]; im = s_cim[sP];
            __syncthreads();
        }
    }

    // ---------------- Z expectations ----------------
    {
        const float pr = re * re + im * im;
        float zv[8];
        #pragma unroll
        for (int q = 0; q < 8; ++q) zv[q] = ((tid >> (7 - q)) & 1) ? -pr : pr;
        #pragma unroll
        for (int off = 32; off >= 1; off >>= 1) {
            #pragma unroll
            for (int q = 0; q < 8; ++q) zv[q] += __shfl_xor(zv[q], off, 64);
        }
        if ((tid & 63) == 0) {
            const int wid = tid >> 6;
            #pragma unroll
            for (int q = 0; q < 8; ++q) s_red[wid * 8 + q] = zv[q];
        }
        __syncthreads();
        if (tid < 8)
            s_q[tid] = s_red[tid] + s_red[8 + tid] + s_red[16 + tid] + s_red[24 + tid];
        __syncthreads();
    }

    // ---------------- head ----------------
    if (tid < 32) {
        float acc = head_b1[tid];
        #pragma unroll
        for (int k = 0; k < 8; ++k) acc += head_w1[tid * 14 + k] * s_q[k];
        #pragma unroll
        for (int k = 0; k < 6; ++k) acc += head_w1[tid * 14 + 8 + k] * scalars[b * 6 + k];
        float h = fmaxf(acc * (head_bn_g[tid] * BN_RSQ) + head_bn_b[tid], 0.0f);
        s_hid2[tid] = h;
    }
    __syncthreads();
    if (tid < 3) {
        float acc = head_b2[tid];
        #pragma unroll
        for (int k = 0; k < 32; ++k) acc += head_w2[tid * 32 + k] * s_hid2[k];
        out[b * 3 + tid] = acc;
    }
}

extern "C" void kernel_launch(void* const* d_in, const int* in_sizes, int n_in,
                              void* d_out, int out_size, void* d_ws, size_t ws_size,
                              hipStream_t stream) {
    const float* flux      = (const float*)d_in[0];
    const float* scalars   = (const float*)d_in[1];
    const float* conv1_w   = (const float*)d_in[2];
    const float* bn1_g     = (const float*)d_in[3];
    const float* bn1_b     = (const float*)d_in[4];
    const float* conv2_w   = (const float*)d_in[5];
    const float* bn2_g     = (const float*)d_in[6];
    const float* bn2_b     = (const float*)d_in[7];
    const float* proj_w1   = (const float*)d_in[8];
    const float* proj_b1   = (const float*)d_in[9];
    const float* proj_w2   = (const float*)d_in[10];
    const float* proj_b2   = (const float*)d_in[11];
    const float* q_weights = (const float*)d_in[12];
    const float* head_w1   = (const float*)d_in[13];
    const float* head_b1   = (const float*)d_in[14];
    const float* head_bn_g = (const float*)d_in[15];
    const float* head_bn_b = (const float*)d_in[16];
    const float* head_w2   = (const float*)d_in[17];
    const float* head_b2   = (const float*)d_in[18];

    const int B = in_sizes[0] / L0;   // 4096

    aec_fused_kernel<<<dim3(B), dim3(256), 0, stream>>>(
        flux, scalars, conv1_w, bn1_g, bn1_b, conv2_w, bn2_g, bn2_b,
        proj_w1, proj_b1, proj_w2, proj_b2, q_weights,
        head_w1, head_b1, head_bn_g, head_bn_b, head_w2, head_b2,
        (float*)d_out);
}

// Round 5
// 399.380 us; speedup vs baseline: 3.6082x; 3.6082x over previous
//
#include <hip/hip_runtime.h>
#include <math.h>

// Problem constants (fixed by reference setup_inputs)
#define L0   4448   // flux length
#define L1P  278    // after conv1(stride4,pad7)->1112 then maxpool4
#define L2   139    // after conv2(stride2,pad3) on 278
#define NQ   8
#define NL   3
#define SD   256

#define H1S  292    // h1 row stride (words); 292%32=4 keeps writes spread

// CNOT-ring permutation (one layer of 8 CNOTs composed). Linear over GF(2):
// perm(x^m) = perm(x)^perm(m).
constexpr int permsrc_c(int x) {
    for (int q = 7; q >= 0; --q) {
        int cb = 7 - q, tb = 7 - ((q + 1) & 7);
        x ^= ((x >> cb) & 1) << tb;
    }
    return x;
}
constexpr int P40 = permsrc_c(0x40);
constexpr int P80 = permsrc_c(0x80);
constexpr int PC0 = permsrc_c(0xC0);

__device__ __forceinline__ int permsrc(int x) {
    #pragma unroll
    for (int q = 7; q >= 0; --q) {
        int cb = 7 - q, tb = 7 - ((q + 1) & 7);
        x ^= ((x >> cb) & 1) << tb;
    }
    return x;
}

// Combined 2-qubit (bits 7 and 6) gate: out = (U0 on bit7)(U1 on bit6) in.
__device__ __forceinline__ void apply2(const float* __restrict__ U0,
                                       const float* __restrict__ U1,
                                       int a7, int a6,
                                       const float vr[4], const float vi[4],
                                       float& re, float& im)
{
    float nr = 0.0f, ni = 0.0f;
    #pragma unroll
    for (int m7 = 0; m7 < 2; ++m7) {
        const float ur0 = U0[(a7 * 2 + (a7 ^ m7)) * 2];
        const float ui0 = U0[(a7 * 2 + (a7 ^ m7)) * 2 + 1];
        #pragma unroll
        for (int m6 = 0; m6 < 2; ++m6) {
            const float ur1 = U1[(a6 * 2 + (a6 ^ m6)) * 2];
            const float ui1 = U1[(a6 * 2 + (a6 ^ m6)) * 2 + 1];
            const float cr = ur0 * ur1 - ui0 * ui1;
            const float ci = ur0 * ui1 + ui0 * ur1;
            const int   id = m7 * 2 + m6;
            nr += cr * vr[id] - ci * vi[id];
            ni += cr * vi[id] + ci * vr[id];
        }
    }
    re = nr; im = ni;
}

// launch_bounds(256,4): 128-VGPR cap — guarantees NO scratch spill (R3 lesson:
// (256,8) forced 64-reg cap -> 5.5 GB scratch traffic, 6x slowdown). Structure
// is trimmed so the allocator can land <=64 naturally; if it does, HW residency
// reaches 8 blocks/CU (LDS 19.7 KB allows it) regardless of the declared bound.
__global__ __launch_bounds__(256, 4)
void aec_fused_kernel(const float* __restrict__ flux,
                      const float* __restrict__ scalars,
                      const float* __restrict__ conv1_w,
                      const float* __restrict__ bn1_g, const float* __restrict__ bn1_b,
                      const float* __restrict__ conv2_w,
                      const float* __restrict__ bn2_g, const float* __restrict__ bn2_b,
                      const float* __restrict__ proj_w1, const float* __restrict__ proj_b1,
                      const float* __restrict__ proj_w2, const float* __restrict__ proj_b2,
                      const float* __restrict__ qw,
                      const float* __restrict__ head_w1, const float* __restrict__ head_b1,
                      const float* __restrict__ head_bn_g, const float* __restrict__ head_bn_b,
                      const float* __restrict__ head_w2, const float* __restrict__ head_b2,
                      float* __restrict__ out)
{
    const int b   = blockIdx.x;
    const int tid = threadIdx.x;

    // h1 [16][292]; dead after stage2, then aliased:
    //   s_hidden Bb[0..63], s_red Bb[64..95], s_q Bb[96..103], s_hid2 Bb[104..135],
    //   cre Bb[256..511], cim Bb[512..767]
    __shared__ __align__(16) float Bb[4676];
    // pool sums feat[32][8] during stage2; s_U[192] after proj1.
    // NOTE (R4 bug): s_U MUST NOT be written before proj1 consumes feat —
    // the early gate-build block that violated this is what failed R4.
    __shared__ __align__(16) float featU[256];

    float* s_hidden = Bb;
    float* s_red    = Bb + 64;
    float* s_q      = Bb + 96;
    float* s_hid2   = Bb + 104;
    float* s_cre    = Bb + 256;
    float* s_cim    = Bb + 512;
    float* s_U      = featU;

    const float BN_RSQ = 0.9999950000374997f;     // 1/sqrt(1+1e-5)

    // ---------------- stage 0: zero feat sums + h1 pads ----------------
    featU[tid] = 0.0f;
    if (tid < 160) {
        int ic = tid / 10, w = tid - ic * 10;
        int off = (w < 4) ? w : (278 + w);        // words {0..3} and {282..287}
        Bb[ic * H1S + off] = 0.0f;
    }

    // ---------------- stage 1: conv1 + bn + relu + maxpool4 -> h1 ----------------
    // 1 channel/thread (low VGPR pressure): c = tid&15, slot = tid>>4.
    // 16 lanes share each window -> coalesced/broadcast global reads.
    {
        const int c    = tid & 15;
        const int slot = tid >> 4;
        const float* frow = flux + (size_t)b * L0;
        float wt[15];
        #pragma unroll
        for (int k = 0; k < 15; ++k) wt[k] = conv1_w[c * 15 + k];
        const float sc  = bn1_g[c] * BN_RSQ;
        const float bt  = bn1_b[c];
        const bool  pos = (sc >= 0.0f);

        for (int p = slot; p < L1P; p += 16) {
            // win[i] <-> flux idx x = 16p - 8 + i, i in [0,28); taps use i 1..27
            float win[28];
            if (p == 0) {
                #pragma unroll
                for (int i = 0; i < 8; ++i) win[i] = 0.0f;
                const float4* src = (const float4*)frow;
                #pragma unroll
                for (int v = 0; v < 5; ++v) {
                    float4 t4 = src[v];
                    win[8+4*v]=t4.x; win[9+4*v]=t4.y; win[10+4*v]=t4.z; win[11+4*v]=t4.w;
                }
            } else if (p == L1P - 1) {
                const float4* src = (const float4*)(frow + 16 * p - 8);
                #pragma unroll
                for (int v = 0; v < 6; ++v) {
                    float4 t4 = src[v];
                    win[4*v]=t4.x; win[1+4*v]=t4.y; win[2+4*v]=t4.z; win[3+4*v]=t4.w;
                }
                #pragma unroll
                for (int i = 24; i < 28; ++i) win[i] = 0.0f;
            } else {
                const float4* src = (const float4*)(frow + 16 * p - 8);
                #pragma unroll
                for (int v = 0; v < 7; ++v) {
                    float4 t4 = src[v];
                    win[4*v]=t4.x; win[1+4*v]=t4.y; win[2+4*v]=t4.z; win[3+4*v]=t4.w;
                }
            }
            float s0 = 0.f, s1 = 0.f, s2 = 0.f, s3 = 0.f;
            #pragma unroll
            for (int k = 0; k < 15; ++k) {
                const float w = wt[k];
                s0 += win[1  + k] * w;
                s1 += win[5  + k] * w;
                s2 += win[9  + k] * w;
                s3 += win[13 + k] * w;
            }
            // maxpool before affine: exact for sc>=0 (use min for sc<0)
            const float mx = fmaxf(fmaxf(s0, s1), fmaxf(s2, s3));
            const float mn = fminf(fminf(s0, s1), fminf(s2, s3));
            const float mm = pos ? mx : mn;
            Bb[c * H1S + 4 + p] = fmaxf(mm * sc + bt, 0.0f);
        }
    }
    __syncthreads();   // stage1 -> stage2 (h1 complete; featU still pure pool sums)

    // ---------------- stage 2: conv2 + bn + relu + fused adaptive pool ----------
    // 2 channels/thread (c2, c2+16), two half-passes of 5 positions each:
    // win[20] (5 b128) + wt 16 regs -> low pressure.
    {
        const int c2 = tid & 15;
        const int g  = tid >> 4;
        const int j0   = (9 * g) & ~1;
        const int npos = ((g == 15) ? L2 : ((9 * (g + 1)) & ~1)) - j0;   // 8/10/5
        float p00 = 0.f, p01 = 0.f, p10 = 0.f, p11 = 0.f;
        int   sBl = 0;

        #pragma unroll
        for (int h = 0; h < 2; ++h) {
            const int nh = npos - 5 * h;      // 5 / {5,3,0}
            if (nh > 0) {
                float acc0[5], acc1[5];
                #pragma unroll
                for (int r = 0; r < 5; ++r) { acc0[r] = 0.0f; acc1[r] = 0.0f; }

                #pragma unroll 1
                for (int t = 0; t < 8; ++t) {
                    #pragma unroll
                    for (int u = 0; u < 2; ++u) {
                        // 8 weights (4 float2) per channel, even base: covers tap
                        // k at wa[k+u] (u=0: floats t*14+0..7; u=1: t*14+6..13)
                        const float2* w0 = (const float2*)(conv2_w + c2 * 112 + t * 14 + 6 * u);
                        const float2* w1 = (const float2*)(conv2_w + (c2 + 16) * 112 + t * 14 + 6 * u);
                        float wa[8], wb[8];
                        #pragma unroll
                        for (int m = 0; m < 4; ++m) {
                            float2 a2 = w0[m]; wa[2*m] = a2.x; wa[2*m+1] = a2.y;
                            float2 b2 = w1[m]; wb[2*m] = b2.x; wb[2*m+1] = b2.y;
                        }
                        const int ic = 2 * t + u;
                        // word base ic*H1S + 2*j0 + 8h (pad +4 folded in); aligned.
                        const float4* src = (const float4*)(Bb + ic * H1S + 2 * j0 + 8 * h);
                        float win[20];
                        #pragma unroll
                        for (int v = 0; v < 5; ++v) {
                            float4 t4 = src[v];
                            win[4*v]=t4.x; win[1+4*v]=t4.y; win[2+4*v]=t4.z; win[3+4*v]=t4.w;
                        }
                        // tap (jj,k): win idx = 2h + 2jj + 1 + k
                        #pragma unroll
                        for (int jj = 0; jj < 5; ++jj) {
                            float s0 = 0.0f, s1 = 0.0f;
                            #pragma unroll
                            for (int k = 0; k < 7; ++k) {
                                const float wv = win[2*h + 2*jj + 1 + k];
                                s0 += wa[k + u] * wv;
                                s1 += wb[k + u] * wv;
                            }
                            acc0[jj] += s0;
                            acc1[jj] += s1;
                        }
                    }
                }
                // epilogue for this half: bn + relu + pool partials
                const float sc0 = bn2_g[c2] * BN_RSQ,      bt0 = bn2_b[c2];
                const float sc1 = bn2_g[c2 + 16] * BN_RSQ, bt1 = bn2_b[c2 + 16];
                const int   b0  = (8 * j0) / 139;
                const int   sB  = (139 * (b0 + 1)) >> 3;
                sBl = b0;
                #pragma unroll
                for (int jj = 0; jj < 5; ++jj) {
                    if (jj < nh) {
                        const int j = j0 + 5 * h + jj;
                        const float v0 = fmaxf(acc0[jj] * sc0 + bt0, 0.0f);
                        const float v1 = fmaxf(acc1[jj] * sc1 + bt1, 0.0f);
                        if (j <= sB) { p00 += v0; p10 += v1; }
                        if (j >= sB) { p01 += v0; p11 += v1; }
                    }
                }
            }
        }
        const int   b0  = sBl;
        const float rc0 = (b0 == 2 || b0 == 5) ? (1.0f/19.0f) : (1.0f/18.0f);
        const float rc1 = (b0 == 1 || b0 == 4) ? (1.0f/19.0f) : (1.0f/18.0f);
        atomicAdd(&featU[c2 * 8 + b0],        p00 * rc0);
        atomicAdd(&featU[(c2 + 16) * 8 + b0], p10 * rc0);
        if (b0 < 7) {
            atomicAdd(&featU[c2 * 8 + b0 + 1],        p01 * rc1);
            atomicAdd(&featU[(c2 + 16) * 8 + b0 + 1], p11 * rc1);
        }
    }
    __syncthreads();

    // ---------------- proj1 (256 -> 64), relu ----------------
    {
        const int o = tid >> 2, s = tid & 3;
        const float4* wg = (const float4*)(proj_w1 + 64 * tid);   // == o*256 + s*64
        const float4* xf = (const float4*)(featU + 64 * s);
        float acc = 0.0f;
        #pragma unroll
        for (int t = 0; t < 16; ++t) {
            float4 w4 = wg[t], x4 = xf[t];
            acc += w4.x * x4.x + w4.y * x4.y + w4.z * x4.z + w4.w * x4.w;
        }
        acc += __shfl_down(acc, 2, 64);
        acc += __shfl_down(acc, 1, 64);
        if (s == 0) s_hidden[o] = fmaxf(acc + proj_b1[o], 0.0f);
    }
    __syncthreads();

    // gate matrices into featU (feat is dead now); published by the
    // __syncthreads() inside the normalize sequence below.
    if (tid < NL * NQ) {
        float phi = qw[tid * 3 + 0], th = qw[tid * 3 + 1], om = qw[tid * 3 + 2];
        float ch = cosf(0.5f * th), sh = sinf(0.5f * th);
        float a  = 0.5f * (phi + om), bb = 0.5f * (phi - om);
        float ca = cosf(a), sa = sinf(a), cb = cosf(bb), sb = sinf(bb);
        float* U = &s_U[tid * 8];
        U[0] =  ca * ch; U[1] = -sa * ch;   // U00
        U[2] = -cb * sh; U[3] = -sb * sh;   // U01
        U[4] =  cb * sh; U[5] = -sb * sh;   // U10
        U[6] =  ca * ch; U[7] =  sa * ch;   // U11
    }

    // ---------------- proj2 (64 -> 256) + L2 normalize ----------------
    float re, im;
    {
        const float4* wg = (const float4*)(proj_w2 + 64 * tid);
        const float4* hf = (const float4*)s_hidden;
        float acc = proj_b2[tid];
        #pragma unroll
        for (int t = 0; t < 16; ++t) {
            float4 w4 = wg[t], x4 = hf[t];
            acc += w4.x * x4.x + w4.y * x4.y + w4.z * x4.z + w4.w * x4.w;
        }
        float ss = acc * acc;
        #pragma unroll
        for (int off = 32; off >= 1; off >>= 1) ss += __shfl_xor(ss, off, 64);
        if ((tid & 63) == 0) s_red[tid >> 6] = ss;
        __syncthreads();                           // also publishes s_U
        float sst = s_red[0] + s_red[1] + s_red[2] + s_red[3];
        float n   = sqrtf(sst);
        float inv = 1.0f / fmaxf(n, 1e-12f);
        float xi  = acc * inv;
        if (n * inv < 1e-8f) xi = 0.0625f;        // uniform 1/sqrt(256)
        re = xi; im = 0.0f;
    }

    // ---------------- quantum circuit ----------------
    const int a7 = (tid >> 7) & 1, a6 = (tid >> 6) & 1;
    const int sP = permsrc(tid);

    // layer 0 combined gate on bits 7,6 (identity permutation before it)
    s_cre[tid] = re; s_cim[tid] = im;
    __syncthreads();
    {
        float vr[4], vi[4];
        vr[0] = re;                vi[0] = im;
        vr[1] = s_cre[tid ^ 0x40]; vi[1] = s_cim[tid ^ 0x40];
        vr[2] = s_cre[tid ^ 0x80]; vi[2] = s_cim[tid ^ 0x80];
        vr[3] = s_cre[tid ^ 0xC0]; vi[3] = s_cim[tid ^ 0xC0];
        __syncthreads();
        apply2(&s_U[0], &s_U[8], a7, a6, vr, vi, re, im);
    }

    #pragma unroll
    for (int l = 0; l < NL; ++l) {
        // gates q = 2..7 (bit positions 5..0): in-wave shuffles
        #pragma unroll
        for (int q = 2; q < NQ; ++q) {
            const float* U = &s_U[(l * NQ + q) * 8];
            const float u00r = U[0], u00i = U[1], u01r = U[2], u01i = U[3];
            const float u10r = U[4], u10i = U[5], u11r = U[6], u11i = U[7];
            const int bp = 7 - q;
            const float pre = __shfl_xor(re, 1 << bp, 64);
            const float pim = __shfl_xor(im, 1 << bp, 64);
            const int bit = (tid >> bp) & 1;
            const float csr = bit ? u11r : u00r;
            const float csi = bit ? u11i : u00i;
            const float cpr = bit ? u10r : u01r;
            const float cpi = bit ? u10i : u01i;
            const float nr = csr * re - csi * im + cpr * pre - cpi * pim;
            const float ni = csr * im + csi * re + cpr * pim + cpi * pre;
            re = nr; im = ni;
        }
        // CNOT-ring permutation, fused with next layer's combined (bit7,bit6) gate
        s_cre[tid] = re; s_cim[tid] = im;
        __syncthreads();
        if (l < NL - 1) {
            float vr[4], vi[4];
            vr[0] = s_cre[sP];       vi[0] = s_cim[sP];
            vr[1] = s_cre[sP ^ P40]; vi[1] = s_cim[sP ^ P40];
            vr[2] = s_cre[sP ^ P80]; vi[2] = s_cim[sP ^ P80];
            vr[3] = s_cre[sP ^ PC0]; vi[3] = s_cim[sP ^ PC0];
            __syncthreads();
            apply2(&s_U[((l + 1) * NQ + 0) * 8], &s_U[((l + 1) * NQ + 1) * 8],
                   a7, a6, vr, vi, re, im);
        } else {
            re = s_cre[sP]; im = s_cim[sP];
            __syncthreads();
        }
    }

    // ---------------- Z expectations ----------------
    {
        const float pr = re * re + im * im;
        float zv[8];
        #pragma unroll
        for (int q = 0; q < 8; ++q) zv[q] = ((tid >> (7 - q)) & 1) ? -pr : pr;
        #pragma unroll
        for (int off = 32; off >= 1; off >>= 1) {
            #pragma unroll
            for (int q = 0; q < 8; ++q) zv[q] += __shfl_xor(zv[q], off, 64);
        }
        if ((tid & 63) == 0) {
            const int wid = tid >> 6;
            #pragma unroll
            for (int q = 0; q < 8; ++q) s_red[wid * 8 + q] = zv[q];
        }
        __syncthreads();
        if (tid < 8)
            s_q[tid] = s_red[tid] + s_red[8 + tid] + s_red[16 + tid] + s_red[24 + tid];
        __syncthreads();
    }

    // ---------------- head ----------------
    if (tid < 32) {
        float acc = head_b1[tid];
        #pragma unroll
        for (int k = 0; k < 8; ++k) acc += head_w1[tid * 14 + k] * s_q[k];
        #pragma unroll
        for (int k = 0; k < 6; ++k) acc += head_w1[tid * 14 + 8 + k] * scalars[b * 6 + k];
        float h = fmaxf(acc * (head_bn_g[tid] * BN_RSQ) + head_bn_b[tid], 0.0f);
        s_hid2[tid] = h;
    }
    __syncthreads();
    if (tid < 3) {
        float acc = head_b2[tid];
        #pragma unroll
        for (int k = 0; k < 32; ++k) acc += head_w2[tid * 32 + k] * s_hid2[k];
        out[b * 3 + tid] = acc;
    }
}

extern "C" void kernel_launch(void* const* d_in, const int* in_sizes, int n_in,
                              void* d_out, int out_size, void* d_ws, size_t ws_size,
                              hipStream_t stream) {
    const float* flux      = (const float*)d_in[0];
    const float* scalars   = (const float*)d_in[1];
    const float* conv1_w   = (const float*)d_in[2];
    const float* bn1_g     = (const float*)d_in[3];
    const float* bn1_b     = (const float*)d_in[4];
    const float* conv2_w   = (const float*)d_in[5];
    const float* bn2_g     = (const float*)d_in[6];
    const float* bn2_b     = (const float*)d_in[7];
    const float* proj_w1   = (const float*)d_in[8];
    const float* proj_b1   = (const float*)d_in[9];
    const float* proj_w2   = (const float*)d_in[10];
    const float* proj_b2   = (const float*)d_in[11];
    const float* q_weights = (const float*)d_in[12];
    const float* head_w1   = (const float*)d_in[13];
    const float* head_b1   = (const float*)d_in[14];
    const float* head_bn_g = (const float*)d_in[15];
    const float* head_bn_b = (const float*)d_in[16];
    const float* head_w2   = (const float*)d_in[17];
    const float* head_b2   = (const float*)d_in[18];

    const int B = in_sizes[0] / L0;   // 4096

    aec_fused_kernel<<<dim3(B), dim3(256), 0, stream>>>(
        flux, scalars, conv1_w, bn1_g, bn1_b, conv2_w, bn2_g, bn2_b,
        proj_w1, proj_b1, proj_w2, proj_b2, q_weights,
        head_w1, head_b1, head_bn_g, head_bn_b, head_w2, head_b2,
        (float*)d_out);
}

// Round 6
// 309.362 us; speedup vs baseline: 4.6581x; 1.2910x over previous
//
#include <hip/hip_runtime.h>
#include <math.h>

// Problem constants (fixed by reference setup_inputs)
#define L0   4448   // flux length
#define L1P  278    // after conv1(stride4,pad7)->1112 then maxpool4
#define L2   139    // after conv2(stride2,pad3) on 278
#define NQ   8
#define NL   3
#define SD   256

#define H1S  292    // h1 row stride (words); 292%32=4 keeps writes spread

// CNOT-ring permutation (one layer of 8 CNOTs composed). Linear over GF(2).
constexpr int permsrc_c(int x) {
    for (int q = 7; q >= 0; --q) {
        int cb = 7 - q, tb = 7 - ((q + 1) & 7);
        x ^= ((x >> cb) & 1) << tb;
    }
    return x;
}
constexpr int P40 = permsrc_c(0x40);
constexpr int P80 = permsrc_c(0x80);
constexpr int PC0 = permsrc_c(0xC0);

__device__ __forceinline__ int permsrc(int x) {
    #pragma unroll
    for (int q = 7; q >= 0; --q) {
        int cb = 7 - q, tb = 7 - ((q + 1) & 7);
        x ^= ((x >> cb) & 1) << tb;
    }
    return x;
}

// Combined 2-qubit (bits 7 and 6) gate: out = (U0 on bit7)(U1 on bit6) in.
__device__ __forceinline__ void apply2(const float* __restrict__ U0,
                                       const float* __restrict__ U1,
                                       int a7, int a6,
                                       const float vr[4], const float vi[4],
                                       float& re, float& im)
{
    float nr = 0.0f, ni = 0.0f;
    #pragma unroll
    for (int m7 = 0; m7 < 2; ++m7) {
        const float ur0 = U0[(a7 * 2 + (a7 ^ m7)) * 2];
        const float ui0 = U0[(a7 * 2 + (a7 ^ m7)) * 2 + 1];
        #pragma unroll
        for (int m6 = 0; m6 < 2; ++m6) {
            const float ur1 = U1[(a6 * 2 + (a6 ^ m6)) * 2];
            const float ui1 = U1[(a6 * 2 + (a6 ^ m6)) * 2 + 1];
            const float cr = ur0 * ur1 - ui0 * ui1;
            const float ci = ur0 * ui1 + ui0 * ur1;
            const int   id = m7 * 2 + m6;
            nr += cr * vr[id] - ci * vi[id];
            ni += cr * vi[id] + ci * vr[id];
        }
    }
    re = nr; im = ni;
}

// (256,4): 128-VGPR cap, far above this code's natural ~64 -> spill impossible
// (R3 lesson: (256,8) forced spill; R5 lesson: "trimmed" bodies made the
// allocator squeeze+spill — these are R2's exact no-spill stage bodies).
__global__ __launch_bounds__(256, 4)
void aec_fused_kernel(const float* __restrict__ flux,
                      const float* __restrict__ scalars,
                      const float* __restrict__ conv1_w,
                      const float* __restrict__ bn1_g, const float* __restrict__ bn1_b,
                      const float* __restrict__ conv2_w,
                      const float* __restrict__ bn2_g, const float* __restrict__ bn2_b,
                      const float* __restrict__ proj_w1, const float* __restrict__ proj_b1,
                      const float* __restrict__ proj_w2, const float* __restrict__ proj_b2,
                      const float* __restrict__ qw,
                      const float* __restrict__ head_w1, const float* __restrict__ head_b1,
                      const float* __restrict__ head_bn_g, const float* __restrict__ head_bn_b,
                      const float* __restrict__ head_w2, const float* __restrict__ head_b2,
                      float* __restrict__ out)
{
    const int b   = blockIdx.x;
    const int tid = threadIdx.x;

    // h1 [16][292]; dead after stage2, then aliased:
    //   s_hidden Bb[0..63], s_red Bb[64..95], s_q Bb[96..103], s_hid2 Bb[104..135],
    //   cre Bb[256..511], cim Bb[512..767]
    __shared__ __align__(16) float Bb[4676];
    // pool sums feat[32][8] during stage2; s_U[192] after proj1.
    // INVARIANT (R4 bug): s_U must not be written until proj1 consumed feat.
    __shared__ __align__(16) float featU[256];

    float* s_hidden = Bb;
    float* s_red    = Bb + 64;
    float* s_q      = Bb + 96;
    float* s_hid2   = Bb + 104;
    float* s_cre    = Bb + 256;
    float* s_cim    = Bb + 512;
    float* s_U      = featU;

    const float BN_RSQ = 0.9999950000374997f;     // 1/sqrt(1+1e-5)

    // ---------------- stage 0: zero feat sums + h1 pads ----------------
    featU[tid] = 0.0f;
    if (tid < 160) {
        int ic = tid / 10, w = tid - ic * 10;
        int off = (w < 4) ? w : (278 + w);        // words {0..3} and {282..287}
        Bb[ic * H1S + off] = 0.0f;
    }

    // ---------------- stage 1: conv1 + bn + relu + maxpool4 -> h1 ----------------
    // R2's exact body: 2 channels/thread (c2, c2+8), slot = tid>>3;
    // 8 lanes share each window -> coalesced global reads.
    {
        const int c2   = tid & 7;
        const int slot = tid >> 3;
        const float* frow = flux + (size_t)b * L0;
        float wt0[15], wt1[15];
        #pragma unroll
        for (int k = 0; k < 15; ++k) {
            wt0[k] = conv1_w[c2 * 15 + k];
            wt1[k] = conv1_w[(c2 + 8) * 15 + k];
        }
        const float sc0 = bn1_g[c2] * BN_RSQ,     bt0 = bn1_b[c2];
        const float sc1 = bn1_g[c2 + 8] * BN_RSQ, bt1 = bn1_b[c2 + 8];

        for (int p = slot; p < L1P; p += 32) {
            // win[i] <-> flux idx x = 16p - 8 + i, i in [0,32); taps use i 1..27
            float win[32];
            if (p == 0) {
                #pragma unroll
                for (int i = 0; i < 8; ++i) win[i] = 0.0f;
                const float4* src = (const float4*)frow;
                #pragma unroll
                for (int v = 0; v < 6; ++v) {
                    float4 t4 = src[v];
                    win[8+4*v]=t4.x; win[9+4*v]=t4.y; win[10+4*v]=t4.z; win[11+4*v]=t4.w;
                }
            } else if (p == L1P - 1) {
                const float4* src = (const float4*)(frow + 16 * p - 8);
                #pragma unroll
                for (int v = 0; v < 6; ++v) {
                    float4 t4 = src[v];
                    win[4*v]=t4.x; win[1+4*v]=t4.y; win[2+4*v]=t4.z; win[3+4*v]=t4.w;
                }
                #pragma unroll
                for (int i = 24; i < 32; ++i) win[i] = 0.0f;
            } else {
                const float4* src = (const float4*)(frow + 16 * p - 8);
                #pragma unroll
                for (int v = 0; v < 8; ++v) {
                    float4 t4 = src[v];
                    win[4*v]=t4.x; win[1+4*v]=t4.y; win[2+4*v]=t4.z; win[3+4*v]=t4.w;
                }
            }
            float m0 = 0.0f, m1 = 0.0f;   // relu outputs >= 0
            #pragma unroll
            for (int j2 = 0; j2 < 4; ++j2) {
                float a0 = 0.0f, a1 = 0.0f;
                #pragma unroll
                for (int k = 0; k < 15; ++k) {
                    float wv = win[4*j2 + 1 + k];
                    a0 += wv * wt0[k];
                    a1 += wv * wt1[k];
                }
                m0 = fmaxf(m0, fmaxf(a0 * sc0 + bt0, 0.0f));
                m1 = fmaxf(m1, fmaxf(a1 * sc1 + bt1, 0.0f));
            }
            Bb[c2 * H1S + 4 + p]       = m0;
            Bb[(c2 + 8) * H1S + 4 + p] = m1;
        }
    }
    __syncthreads();   // h1 complete; featU still pure pool sums

    // ---------------- stage 2: conv2 + bn + relu + fused adaptive pool ----------
    // R2's exact conv body: 2 channels/thread (c2, c2+16), 10 positions, win[28];
    // epilogue accumulates pool partials (<=2 bins) + 4 LDS atomicAdds instead
    // of writing h2 (kills the 18.6 KB h2 array and the separate pool pass).
    {
        const int c2 = tid & 15;
        const int g  = tid >> 4;
        const int j0   = (9 * g) & ~1;
        const int npos = ((g == 15) ? L2 : ((9 * (g + 1)) & ~1)) - j0;   // 8/10/5
        float acc0[10], acc1[10];
        #pragma unroll
        for (int r = 0; r < 10; ++r) { acc0[r] = 0.0f; acc1[r] = 0.0f; }

        #pragma unroll 1
        for (int t = 0; t < 8; ++t) {              // ic chunk of 2
            float wt0[14], wt1[14];
            const float2* w0 = (const float2*)(conv2_w + c2 * 112 + t * 14);
            const float2* w1 = (const float2*)(conv2_w + (c2 + 16) * 112 + t * 14);
            #pragma unroll
            for (int m = 0; m < 7; ++m) {
                float2 a2 = w0[m]; wt0[2*m] = a2.x; wt0[2*m+1] = a2.y;
                float2 b2 = w1[m]; wt1[2*m] = b2.x; wt1[2*m+1] = b2.y;
            }
            #pragma unroll
            for (int u = 0; u < 2; ++u) {
                const int ic = 2 * t + u;
                // win[i] <-> x = 2*j0 - 4 + i; tap (jj,k) -> i = 1 + 2*jj + k
                float win[28];
                const float4* src = (const float4*)(Bb + ic * H1S + 2 * j0);
                #pragma unroll
                for (int v = 0; v < 7; ++v) {
                    float4 t4 = src[v];
                    win[4*v]=t4.x; win[1+4*v]=t4.y; win[2+4*v]=t4.z; win[3+4*v]=t4.w;
                }
                #pragma unroll
                for (int jj = 0; jj < 10; ++jj) {
                    float s0 = 0.0f, s1 = 0.0f;
                    #pragma unroll
                    for (int k = 0; k < 7; ++k) {
                        float wv = win[1 + 2*jj + k];
                        s0 += wt0[u*7 + k] * wv;
                        s1 += wt1[u*7 + k] * wv;
                    }
                    acc0[jj] += s0;
                    acc1[jj] += s1;
                }
            }
        }
        // fused-pool epilogue (verified R5): bin widths 18, except bins 2,5 = 19;
        // boundary pos sB belongs to both bins b0 and b0+1.
        const float sc0 = bn2_g[c2] * BN_RSQ,      bt0 = bn2_b[c2];
        const float sc1 = bn2_g[c2 + 16] * BN_RSQ, bt1 = bn2_b[c2 + 16];
        const int   b0  = (8 * j0) / 139;
        const int   sB  = (139 * (b0 + 1)) >> 3;
        const float rc0 = (b0 == 2 || b0 == 5) ? (1.0f/19.0f) : (1.0f/18.0f);
        const float rc1 = (b0 == 1 || b0 == 4) ? (1.0f/19.0f) : (1.0f/18.0f);
        float p00 = 0.f, p01 = 0.f, p10 = 0.f, p11 = 0.f;
        #pragma unroll
        for (int jj = 0; jj < 10; ++jj) {
            if (jj < npos) {
                const int j = j0 + jj;
                const float v0 = fmaxf(acc0[jj] * sc0 + bt0, 0.0f);
                const float v1 = fmaxf(acc1[jj] * sc1 + bt1, 0.0f);
                if (j <= sB) { p00 += v0; p10 += v1; }
                if (j >= sB) { p01 += v0; p11 += v1; }
            }
        }
        atomicAdd(&featU[c2 * 8 + b0],        p00 * rc0);
        atomicAdd(&featU[(c2 + 16) * 8 + b0], p10 * rc0);
        if (b0 < 7) {
            atomicAdd(&featU[c2 * 8 + b0 + 1],        p01 * rc1);
            atomicAdd(&featU[(c2 + 16) * 8 + b0 + 1], p11 * rc1);
        }
    }
    __syncthreads();

    // ---------------- proj1 (256 -> 64), relu ----------------
    {
        const int o = tid >> 2, s = tid & 3;
        const float4* wg = (const float4*)(proj_w1 + 64 * tid);   // == o*256 + s*64
        const float4* xf = (const float4*)(featU + 64 * s);
        float acc = 0.0f;
        #pragma unroll
        for (int t = 0; t < 16; ++t) {
            float4 w4 = wg[t], x4 = xf[t];
            acc += w4.x * x4.x + w4.y * x4.y + w4.z * x4.z + w4.w * x4.w;
        }
        acc += __shfl_down(acc, 2, 64);
        acc += __shfl_down(acc, 1, 64);
        if (s == 0) s_hidden[o] = fmaxf(acc + proj_b1[o], 0.0f);
    }
    __syncthreads();

    // gate matrices into featU (feat is dead NOW — only safe place);
    // published by the __syncthreads() inside the normalize sequence below.
    if (tid < NL * NQ) {
        float phi = qw[tid * 3 + 0], th = qw[tid * 3 + 1], om = qw[tid * 3 + 2];
        float ch = cosf(0.5f * th), sh = sinf(0.5f * th);
        float a  = 0.5f * (phi + om), bb = 0.5f * (phi - om);
        float ca = cosf(a), sa = sinf(a), cb = cosf(bb), sb = sinf(bb);
        float* U = &s_U[tid * 8];
        U[0] =  ca * ch; U[1] = -sa * ch;   // U00
        U[2] = -cb * sh; U[3] = -sb * sh;   // U01
        U[4] =  cb * sh; U[5] = -sb * sh;   // U10
        U[6] =  ca * ch; U[7] =  sa * ch;   // U11
    }

    // ---------------- proj2 (64 -> 256) + L2 normalize ----------------
    float re, im;
    {
        const float4* wg = (const float4*)(proj_w2 + 64 * tid);
        const float4* hf = (const float4*)s_hidden;
        float acc = proj_b2[tid];
        #pragma unroll
        for (int t = 0; t < 16; ++t) {
            float4 w4 = wg[t], x4 = hf[t];
            acc += w4.x * x4.x + w4.y * x4.y + w4.z * x4.z + w4.w * x4.w;
        }
        float ss = acc * acc;
        #pragma unroll
        for (int off = 32; off >= 1; off >>= 1) ss += __shfl_xor(ss, off, 64);
        if ((tid & 63) == 0) s_red[tid >> 6] = ss;
        __syncthreads();                           // also publishes s_U
        float sst = s_red[0] + s_red[1] + s_red[2] + s_red[3];
        float n   = sqrtf(sst);
        float inv = 1.0f / fmaxf(n, 1e-12f);
        float xi  = acc * inv;
        if (n * inv < 1e-8f) xi = 0.0625f;        // uniform 1/sqrt(256)
        re = xi; im = 0.0f;
    }

    // ---------------- quantum circuit (R5-verified barrier-dieted form) --------
    const int a7 = (tid >> 7) & 1, a6 = (tid >> 6) & 1;
    const int sP = permsrc(tid);

    // layer 0 combined gate on bits 7,6 (identity permutation before it)
    s_cre[tid] = re; s_cim[tid] = im;
    __syncthreads();
    {
        float vr[4], vi[4];
        vr[0] = re;                vi[0] = im;
        vr[1] = s_cre[tid ^ 0x40]; vi[1] = s_cim[tid ^ 0x40];
        vr[2] = s_cre[tid ^ 0x80]; vi[2] = s_cim[tid ^ 0x80];
        vr[3] = s_cre[tid ^ 0xC0]; vi[3] = s_cim[tid ^ 0xC0];
        __syncthreads();
        apply2(&s_U[0], &s_U[8], a7, a6, vr, vi, re, im);
    }

    #pragma unroll
    for (int l = 0; l < NL; ++l) {
        // gates q = 2..7 (bit positions 5..0): in-wave shuffles
        #pragma unroll
        for (int q = 2; q < NQ; ++q) {
            const float* U = &s_U[(l * NQ + q) * 8];
            const float u00r = U[0], u00i = U[1], u01r = U[2], u01i = U[3];
            const float u10r = U[4], u10i = U[5], u11r = U[6], u11i = U[7];
            const int bp = 7 - q;
            const float pre = __shfl_xor(re, 1 << bp, 64);
            const float pim = __shfl_xor(im, 1 << bp, 64);
            const int bit = (tid >> bp) & 1;
            const float csr = bit ? u11r : u00r;
            const float csi = bit ? u11i : u00i;
            const float cpr = bit ? u10r : u01r;
            const float cpi = bit ? u10i : u01i;
            const float nr = csr * re - csi * im + cpr * pre - cpi * pim;
            const float ni = csr * im + csi * re + cpr * pim + cpi * pre;
            re = nr; im = ni;
        }
        // CNOT-ring permutation, fused with next layer's combined (bit7,bit6) gate
        s_cre[tid] = re; s_cim[tid] = im;
        __syncthreads();
        if (l < NL - 1) {
            float vr[4], vi[4];
            vr[0] = s_cre[sP];       vi[0] = s_cim[sP];
            vr[1] = s_cre[sP ^ P40]; vi[1] = s_cim[sP ^ P40];
            vr[2] = s_cre[sP ^ P80]; vi[2] = s_cim[sP ^ P80];
            vr[3] = s_cre[sP ^ PC0]; vi[3] = s_cim[sP ^ PC0];
            __syncthreads();
            apply2(&s_U[((l + 1) * NQ + 0) * 8], &s_U[((l + 1) * NQ + 1) * 8],
                   a7, a6, vr, vi, re, im);
        } else {
            re = s_cre[sP]; im = s_cim[sP];
            __syncthreads();
        }
    }

    // ---------------- Z expectations ----------------
    {
        const float pr = re * re + im * im;
        float zv[8];
        #pragma unroll
        for (int q = 0; q < 8; ++q) zv[q] = ((tid >> (7 - q)) & 1) ? -pr : pr;
        #pragma unroll
        for (int off = 32; off >= 1; off >>= 1) {
            #pragma unroll
            for (int q = 0; q < 8; ++q) zv[q] += __shfl_xor(zv[q], off, 64);
        }
        if ((tid & 63) == 0) {
            const int wid = tid >> 6;
            #pragma unroll
            for (int q = 0; q < 8; ++q) s_red[wid * 8 + q] = zv[q];
        }
        __syncthreads();
        if (tid < 8)
            s_q[tid] = s_red[tid] + s_red[8 + tid] + s_red[16 + tid] + s_red[24 + tid];
        __syncthreads();
    }

    // ---------------- head ----------------
    if (tid < 32) {
        float acc = head_b1[tid];
        #pragma unroll
        for (int k = 0; k < 8; ++k) acc += head_w1[tid * 14 + k] * s_q[k];
        #pragma unroll
        for (int k = 0; k < 6; ++k) acc += head_w1[tid * 14 + 8 + k] * scalars[b * 6 + k];
        float h = fmaxf(acc * (head_bn_g[tid] * BN_RSQ) + head_bn_b[tid], 0.0f);
        s_hid2[tid] = h;
    }
    __syncthreads();
    if (tid < 3) {
        float acc = head_b2[tid];
        #pragma unroll
        for (int k = 0; k < 32; ++k) acc += head_w2[tid * 32 + k] * s_hid2[k];
        out[b * 3 + tid] = acc;
    }
}

extern "C" void kernel_launch(void* const* d_in, const int* in_sizes, int n_in,
                              void* d_out, int out_size, void* d_ws, size_t ws_size,
                              hipStream_t stream) {
    const float* flux      = (const float*)d_in[0];
    const float* scalars   = (const float*)d_in[1];
    const float* conv1_w   = (const float*)d_in[2];
    const float* bn1_g     = (const float*)d_in[3];
    const float* bn1_b     = (const float*)d_in[4];
    const float* conv2_w   = (const float*)d_in[5];
    const float* bn2_g     = (const float*)d_in[6];
    const float* bn2_b     = (const float*)d_in[7];
    const float* proj_w1   = (const float*)d_in[8];
    const float* proj_b1   = (const float*)d_in[9];
    const float* proj_w2   = (const float*)d_in[10];
    const float* proj_b2   = (const float*)d_in[11];
    const float* q_weights = (const float*)d_in[12];
    const float* head_w1   = (const float*)d_in[13];
    const float* head_b1   = (const float*)d_in[14];
    const float* head_bn_g = (const float*)d_in[15];
    const float* head_bn_b = (const float*)d_in[16];
    const float* head_w2   = (const float*)d_in[17];
    const float* head_b2   = (const float*)d_in[18];

    const int B = in_sizes[0] / L0;   // 4096

    aec_fused_kernel<<<dim3(B), dim3(256), 0, stream>>>(
        flux, scalars, conv1_w, bn1_g, bn1_b, conv2_w, bn2_g, bn2_b,
        proj_w1, proj_b1, proj_w2, proj_b2, q_weights,
        head_w1, head_b1, head_bn_g, head_bn_b, head_w2, head_b2,
        (float*)d_out);
}

// Round 7
// 265.700 us; speedup vs baseline: 5.4236x; 1.1643x over previous
//
#include <hip/hip_runtime.h>
#include <math.h>

// Problem constants (fixed by reference setup_inputs)
#define L0   4448   // flux length
#define L1P  278    // after conv1(stride4,pad7)->1112 then maxpool4
#define L2   139    // after conv2(stride2,pad3) on 278
#define NQ   8
#define NL   3
#define SD   256

// LDS word-offset map (float S[5292] = 21168 B):
//  h1T bf16 [286 rows][20 ic-stride]  words 0..2859   (row = h1 pos + 4)
//  Wb  bf16 [32 oc][136 K'-stride]    words 2860..5035 (K' = k*16+ic, k=7 zero)
//  featU f32 [256]                    words 5036..5291 (pool sums, then s_U)
// Aliases into dead h1T after conv2: s_hidden 0..63, s_red 64..95, s_q 96..103,
//  s_hid2 104..135, cre 256..511, cim 512..767.
#define WBW  2860
#define FTW  5036

typedef __attribute__((ext_vector_type(4))) short short4v;
typedef __attribute__((ext_vector_type(8))) short short8;
typedef __attribute__((ext_vector_type(4))) float f32x4;
union FragU { short8 v; short4v h[2]; };

__device__ __forceinline__ short f2bf(float x) {   // fp32 -> bf16 (RNE)
    unsigned u = __float_as_uint(x);
    u += 0x7FFFu + ((u >> 16) & 1u);
    return (short)(u >> 16);
}

// CNOT-ring permutation (one layer of 8 CNOTs composed). Linear over GF(2).
constexpr int permsrc_c(int x) {
    for (int q = 7; q >= 0; --q) {
        int cb = 7 - q, tb = 7 - ((q + 1) & 7);
        x ^= ((x >> cb) & 1) << tb;
    }
    return x;
}
constexpr int P40 = permsrc_c(0x40);
constexpr int P80 = permsrc_c(0x80);
constexpr int PC0 = permsrc_c(0xC0);

__device__ __forceinline__ int permsrc(int x) {
    #pragma unroll
    for (int q = 7; q >= 0; --q) {
        int cb = 7 - q, tb = 7 - ((q + 1) & 7);
        x ^= ((x >> cb) & 1) << tb;
    }
    return x;
}

// Combined 2-qubit (bits 7 and 6) gate: out = (U0 on bit7)(U1 on bit6) in.
__device__ __forceinline__ void apply2(const float* __restrict__ U0,
                                       const float* __restrict__ U1,
                                       int a7, int a6,
                                       const float vr[4], const float vi[4],
                                       float& re, float& im)
{
    float nr = 0.0f, ni = 0.0f;
    #pragma unroll
    for (int m7 = 0; m7 < 2; ++m7) {
        const float ur0 = U0[(a7 * 2 + (a7 ^ m7)) * 2];
        const float ui0 = U0[(a7 * 2 + (a7 ^ m7)) * 2 + 1];
        #pragma unroll
        for (int m6 = 0; m6 < 2; ++m6) {
            const float ur1 = U1[(a6 * 2 + (a6 ^ m6)) * 2];
            const float ui1 = U1[(a6 * 2 + (a6 ^ m6)) * 2 + 1];
            const float cr = ur0 * ur1 - ui0 * ui1;
            const float ci = ur0 * ui1 + ui0 * ur1;
            const int   id = m7 * 2 + m6;
            nr += cr * vr[id] - ci * vi[id];
            ni += cr * vi[id] + ci * vr[id];
        }
    }
    re = nr; im = ni;
}

__global__ __launch_bounds__(256, 4)
void aec_fused_kernel(const float* __restrict__ flux,
                      const float* __restrict__ scalars,
                      const float* __restrict__ conv1_w,
                      const float* __restrict__ bn1_g, const float* __restrict__ bn1_b,
                      const float* __restrict__ conv2_w,
                      const float* __restrict__ bn2_g, const float* __restrict__ bn2_b,
                      const float* __restrict__ proj_w1, const float* __restrict__ proj_b1,
                      const float* __restrict__ proj_w2, const float* __restrict__ proj_b2,
                      const float* __restrict__ qw,
                      const float* __restrict__ head_w1, const float* __restrict__ head_b1,
                      const float* __restrict__ head_bn_g, const float* __restrict__ head_bn_b,
                      const float* __restrict__ head_w2, const float* __restrict__ head_b2,
                      float* __restrict__ out)
{
    const int b   = blockIdx.x;
    const int tid = threadIdx.x;

    __shared__ __align__(16) float S[5292];

    float* s_hidden = S;
    float* s_red    = S + 64;
    float* s_q      = S + 96;
    float* s_hid2   = S + 104;
    float* s_cre    = S + 256;
    float* s_cim    = S + 512;
    float* featU    = S + FTW;
    float* s_U      = S + FTW;      // gates overwrite featU AFTER proj1 (R4 bug!)

    const float BN_RSQ = 0.9999950000374997f;     // 1/sqrt(1+1e-5)

    // ---------------- stage 0: zero pads/featU + build bf16 weight matrix -------
    if (tid < 40)            S[tid] = 0.0f;             // h1T rows 0..3 (pos -4..-1)
    else if (tid < 80)       S[2820 + tid - 40] = 0.0f; // h1T rows 282..285
    featU[tid] = 0.0f;
    {
        // Wb[oc][K'=k*16+ic] bf16, row stride 136; k==7 row is the zero pad.
        const int oc = tid >> 3;
        const int k  = tid & 7;
        short tmp[16];
        #pragma unroll
        for (int ic = 0; ic < 16; ++ic)
            tmp[ic] = (k < 7) ? f2bf(conv2_w[oc * 112 + ic * 7 + k]) : (short)0;
        short8 w0, w1;
        #pragma unroll
        for (int e = 0; e < 8; ++e) { w0[e] = tmp[e]; w1[e] = tmp[8 + e]; }
        short8* dst = (short8*)((char*)(S + WBW) + (oc * 136 + k * 16) * 2);
        dst[0] = w0; dst[1] = w1;
    }

    // ---------------- stage 1: conv1 + bn + relu + maxpool4 -> h1T (bf16) -------
    // R2's verified body; only the store changed (bf16, [pos][ic] layout).
    {
        const int c2   = tid & 7;
        const int slot = tid >> 3;
        const float* frow = flux + (size_t)b * L0;
        short* h1w = (short*)S;
        float wt0[15], wt1[15];
        #pragma unroll
        for (int k = 0; k < 15; ++k) {
            wt0[k] = conv1_w[c2 * 15 + k];
            wt1[k] = conv1_w[(c2 + 8) * 15 + k];
        }
        const float sc0 = bn1_g[c2] * BN_RSQ,     bt0 = bn1_b[c2];
        const float sc1 = bn1_g[c2 + 8] * BN_RSQ, bt1 = bn1_b[c2 + 8];

        for (int p = slot; p < L1P; p += 32) {
            float win[32];
            if (p == 0) {
                #pragma unroll
                for (int i = 0; i < 8; ++i) win[i] = 0.0f;
                const float4* src = (const float4*)frow;
                #pragma unroll
                for (int v = 0; v < 6; ++v) {
                    float4 t4 = src[v];
                    win[8+4*v]=t4.x; win[9+4*v]=t4.y; win[10+4*v]=t4.z; win[11+4*v]=t4.w;
                }
            } else if (p == L1P - 1) {
                const float4* src = (const float4*)(frow + 16 * p - 8);
                #pragma unroll
                for (int v = 0; v < 6; ++v) {
                    float4 t4 = src[v];
                    win[4*v]=t4.x; win[1+4*v]=t4.y; win[2+4*v]=t4.z; win[3+4*v]=t4.w;
                }
                #pragma unroll
                for (int i = 24; i < 32; ++i) win[i] = 0.0f;
            } else {
                const float4* src = (const float4*)(frow + 16 * p - 8);
                #pragma unroll
                for (int v = 0; v < 8; ++v) {
                    float4 t4 = src[v];
                    win[4*v]=t4.x; win[1+4*v]=t4.y; win[2+4*v]=t4.z; win[3+4*v]=t4.w;
                }
            }
            float m0 = 0.0f, m1 = 0.0f;
            #pragma unroll
            for (int j2 = 0; j2 < 4; ++j2) {
                float a0 = 0.0f, a1 = 0.0f;
                #pragma unroll
                for (int k = 0; k < 15; ++k) {
                    float wv = win[4*j2 + 1 + k];
                    a0 += wv * wt0[k];
                    a1 += wv * wt1[k];
                }
                m0 = fmaxf(m0, fmaxf(a0 * sc0 + bt0, 0.0f));
                m1 = fmaxf(m1, fmaxf(a1 * sc1 + bt1, 0.0f));
            }
            h1w[(4 + p) * 20 + c2]     = f2bf(m0);
            h1w[(4 + p) * 20 + c2 + 8] = f2bf(m1);
        }
    }
    __syncthreads();   // h1T + Wb complete; featU still pure pool sums

    // ---------------- stage 2: conv2 as MFMA GEMM + bn/relu + fused pool --------
    // C[32 oc][144 j] = Wb[32][128] x X[128][144], X[K'][j] = h1T[2j+1+k][ic].
    // 16x16x32 bf16 MFMA; A: m=lane&15 (oc), B: n=lane&15 (j), K'-octet g*8;
    // D: row (oc) = g*4+reg, col (j) = lane&15  [m89-verified layouts].
    {
        const int lane = tid & 63;
        const int wid  = tid >> 6;
        const int col  = lane & 15;
        const int g    = (lane >> 4) & 3;
        const short* h1s = (const short*)S;
        const char*  wbc = (const char*)(S + WBW);

        for (int nt = wid; nt < 9; nt += 4) {
            const int n0 = nt * 16;
            const int j  = n0 + col;
            f32x4 acc0 = {0.f,0.f,0.f,0.f}, acc1 = {0.f,0.f,0.f,0.f};
            #pragma unroll
            for (int kb = 0; kb < 4; ++kb) {
                const int k   = 2 * kb + (g >> 1);
                const int ic0 = (g & 1) * 8;
                const int row = 2 * j + 1 + k;            // (>138-j rows unused: masked)
                FragU bu;
                bu.h[0] = *(const short4v*)(h1s + row * 20 + ic0);
                bu.h[1] = *(const short4v*)(h1s + row * 20 + ic0 + 4);
                const short8 a0 = *(const short8*)(wbc + (col * 136        + kb*32 + g*8) * 2);
                const short8 a1 = *(const short8*)(wbc + ((16 + col) * 136 + kb*32 + g*8) * 2);
                acc0 = __builtin_amdgcn_mfma_f32_16x16x32_bf16(a0, bu.v, acc0, 0, 0, 0);
                acc1 = __builtin_amdgcn_mfma_f32_16x16x32_bf16(a1, bu.v, acc1, 0, 0, 0);
            }
            // fused adaptive-pool epilogue (verified bin logic, reduced over cols)
            const int   bA  = (8 * n0) / 139;
            const int   sB  = (139 * (bA + 1)) >> 3;      // j<=sB -> bA; j>=sB -> bA+1
            const float rcA = (bA == 2 || bA == 5) ? (1.0f/19.0f) : (1.0f/18.0f);
            const float rcB = (bA == 1 || bA == 4) ? (1.0f/19.0f) : (1.0f/18.0f);
            const int   g4  = g * 4;
            #pragma unroll
            for (int half = 0; half < 2; ++half) {
                const int oc0 = half * 16;
                const float4 sc4 = *(const float4*)(bn2_g + oc0 + g4);
                const float4 bt4 = *(const float4*)(bn2_b + oc0 + g4);
                const float scs[4] = {sc4.x, sc4.y, sc4.z, sc4.w};
                const float bts[4] = {bt4.x, bt4.y, bt4.z, bt4.w};
                const f32x4 A = half ? acc1 : acc0;
                #pragma unroll
                for (int r = 0; r < 4; ++r) {
                    float v = fmaxf(A[r] * (scs[r] * BN_RSQ) + bts[r], 0.0f);
                    if (j > 138) v = 0.0f;
                    float va = (j <= sB) ? v * rcA : 0.0f;
                    float vb = (j >= sB) ? v * rcB : 0.0f;
                    va += __shfl_xor(va, 1, 64); va += __shfl_xor(va, 2, 64);
                    va += __shfl_xor(va, 4, 64); va += __shfl_xor(va, 8, 64);
                    vb += __shfl_xor(vb, 1, 64); vb += __shfl_xor(vb, 2, 64);
                    vb += __shfl_xor(vb, 4, 64); vb += __shfl_xor(vb, 8, 64);
                    if (col == 0) {
                        atomicAdd(&featU[(oc0 + g4 + r) * 8 + bA], va);
                        if (bA < 7)
                            atomicAdd(&featU[(oc0 + g4 + r) * 8 + bA + 1], vb);
                    }
                }
            }
        }
    }
    __syncthreads();

    // ---------------- proj1 (256 -> 64), relu ----------------
    {
        const int o = tid >> 2, s = tid & 3;
        const float4* wg = (const float4*)(proj_w1 + 64 * tid);   // == o*256 + s*64
        const float4* xf = (const float4*)(featU + 64 * s);
        float acc = 0.0f;
        #pragma unroll
        for (int t = 0; t < 16; ++t) {
            float4 w4 = wg[t], x4 = xf[t];
            acc += w4.x * x4.x + w4.y * x4.y + w4.z * x4.z + w4.w * x4.w;
        }
        acc += __shfl_down(acc, 2, 64);
        acc += __shfl_down(acc, 1, 64);
        if (s == 0) s_hidden[o] = fmaxf(acc + proj_b1[o], 0.0f);
    }
    __syncthreads();

    // gate matrices into featU (feat consumed — only safe place, R4 invariant);
    // published by the __syncthreads() inside the normalize sequence below.
    if (tid < NL * NQ) {
        float phi = qw[tid * 3 + 0], th = qw[tid * 3 + 1], om = qw[tid * 3 + 2];
        float ch = cosf(0.5f * th), sh = sinf(0.5f * th);
        float a  = 0.5f * (phi + om), bb = 0.5f * (phi - om);
        float ca = cosf(a), sa = sinf(a), cb = cosf(bb), sb = sinf(bb);
        float* U = &s_U[tid * 8];
        U[0] =  ca * ch; U[1] = -sa * ch;   // U00
        U[2] = -cb * sh; U[3] = -sb * sh;   // U01
        U[4] =  cb * sh; U[5] = -sb * sh;   // U10
        U[6] =  ca * ch; U[7] =  sa * ch;   // U11
    }

    // ---------------- proj2 (64 -> 256) + L2 normalize ----------------
    float re, im;
    {
        const float4* wg = (const float4*)(proj_w2 + 64 * tid);
        const float4* hf = (const float4*)s_hidden;
        float acc = proj_b2[tid];
        #pragma unroll
        for (int t = 0; t < 16; ++t) {
            float4 w4 = wg[t], x4 = hf[t];
            acc += w4.x * x4.x + w4.y * x4.y + w4.z * x4.z + w4.w * x4.w;
        }
        float ss = acc * acc;
        #pragma unroll
        for (int off = 32; off >= 1; off >>= 1) ss += __shfl_xor(ss, off, 64);
        if ((tid & 63) == 0) s_red[tid >> 6] = ss;
        __syncthreads();                           // also publishes s_U
        float sst = s_red[0] + s_red[1] + s_red[2] + s_red[3];
        float n   = sqrtf(sst);
        float inv = 1.0f / fmaxf(n, 1e-12f);
        float xi  = acc * inv;
        if (n * inv < 1e-8f) xi = 0.0625f;        // uniform 1/sqrt(256)
        re = xi; im = 0.0f;
    }

    // ---------------- quantum circuit ----------------
    const int a7 = (tid >> 7) & 1, a6 = (tid >> 6) & 1;
    const int sP = permsrc(tid);

    s_cre[tid] = re; s_cim[tid] = im;
    __syncthreads();
    {
        float vr[4], vi[4];
        vr[0] = re;                vi[0] = im;
        vr[1] = s_cre[tid ^ 0x40]; vi[1] = s_cim[tid ^ 0x40];
        vr[2] = s_cre[tid ^ 0x80]; vi[2] = s_cim[tid ^ 0x80];
        vr[3] = s_cre[tid ^ 0xC0]; vi[3] = s_cim[tid ^ 0xC0];
        __syncthreads();
        apply2(&s_U[0], &s_U[8], a7, a6, vr, vi, re, im);
    }

    #pragma unroll
    for (int l = 0; l < NL; ++l) {
        #pragma unroll
        for (int q = 2; q < NQ; ++q) {
            const float* U = &s_U[(l * NQ + q) * 8];
            const float u00r = U[0], u00i = U[1], u01r = U[2], u01i = U[3];
            const float u10r = U[4], u10i = U[5], u11r = U[6], u11i = U[7];
            const int bp = 7 - q;
            const float pre = __shfl_xor(re, 1 << bp, 64);
            const float pim = __shfl_xor(im, 1 << bp, 64);
            const int bit = (tid >> bp) & 1;
            const float csr = bit ? u11r : u00r;
            const float csi = bit ? u11i : u00i;
            const float cpr = bit ? u10r : u01r;
            const float cpi = bit ? u10i : u01i;
            const float nr = csr * re - csi * im + cpr * pre - cpi * pim;
            const float ni = csr * im + csi * re + cpr * pim + cpi * pre;
            re = nr; im = ni;
        }
        s_cre[tid] = re; s_cim[tid] = im;
        __syncthreads();
        if (l < NL - 1) {
            float vr[4], vi[4];
            vr[0] = s_cre[sP];       vi[0] = s_cim[sP];
            vr[1] = s_cre[sP ^ P40]; vi[1] = s_cim[sP ^ P40];
            vr[2] = s_cre[sP ^ P80]; vi[2] = s_cim[sP ^ P80];
            vr[3] = s_cre[sP ^ PC0]; vi[3] = s_cim[sP ^ PC0];
            __syncthreads();
            apply2(&s_U[((l + 1) * NQ + 0) * 8], &s_U[((l + 1) * NQ + 1) * 8],
                   a7, a6, vr, vi, re, im);
        } else {
            re = s_cre[sP]; im = s_cim[sP];
            __syncthreads();
        }
    }

    // ---------------- Z expectations ----------------
    {
        const float pr = re * re + im * im;
        float zv[8];
        #pragma unroll
        for (int q = 0; q < 8; ++q) zv[q] = ((tid >> (7 - q)) & 1) ? -pr : pr;
        #pragma unroll
        for (int off = 32; off >= 1; off >>= 1) {
            #pragma unroll
            for (int q = 0; q < 8; ++q) zv[q] += __shfl_xor(zv[q], off, 64);
        }
        if ((tid & 63) == 0) {
            const int wid = tid >> 6;
            #pragma unroll
            for (int q = 0; q < 8; ++q) s_red[wid * 8 + q] = zv[q];
        }
        __syncthreads();
        if (tid < 8)
            s_q[tid] = s_red[tid] + s_red[8 + tid] + s_red[16 + tid] + s_red[24 + tid];
        __syncthreads();
    }

    // ---------------- head ----------------
    if (tid < 32) {
        float acc = head_b1[tid];
        #pragma unroll
        for (int k = 0; k < 8; ++k) acc += head_w1[tid * 14 + k] * s_q[k];
        #pragma unroll
        for (int k = 0; k < 6; ++k) acc += head_w1[tid * 14 + 8 + k] * scalars[b * 6 + k];
        float h = fmaxf(acc * (head_bn_g[tid] * BN_RSQ) + head_bn_b[tid], 0.0f);
        s_hid2[tid] = h;
    }
    __syncthreads();
    if (tid < 3) {
        float acc = head_b2[tid];
        #pragma unroll
        for (int k = 0; k < 32; ++k) acc += head_w2[tid * 32 + k] * s_hid2[k];
        out[b * 3 + tid] = acc;
    }
}

extern "C" void kernel_launch(void* const* d_in, const int* in_sizes, int n_in,
                              void* d_out, int out_size, void* d_ws, size_t ws_size,
                              hipStream_t stream) {
    const float* flux      = (const float*)d_in[0];
    const float* scalars   = (const float*)d_in[1];
    const float* conv1_w   = (const float*)d_in[2];
    const float* bn1_g     = (const float*)d_in[3];
    const float* bn1_b     = (const float*)d_in[4];
    const float* conv2_w   = (const float*)d_in[5];
    const float* bn2_g     = (const float*)d_in[6];
    const float* bn2_b     = (const float*)d_in[7];
    const float* proj_w1   = (const float*)d_in[8];
    const float* proj_b1   = (const float*)d_in[9];
    const float* proj_w2   = (const float*)d_in[10];
    const float* proj_b2   = (const float*)d_in[11];
    const float* q_weights = (const float*)d_in[12];
    const float* head_w1   = (const float*)d_in[13];
    const float* head_b1   = (const float*)d_in[14];
    const float* head_bn_g = (const float*)d_in[15];
    const float* head_bn_b = (const float*)d_in[16];
    const float* head_w2   = (const float*)d_in[17];
    const float* head_b2   = (const float*)d_in[18];

    const int B = in_sizes[0] / L0;   // 4096

    aec_fused_kernel<<<dim3(B), dim3(256), 0, stream>>>(
        flux, scalars, conv1_w, bn1_g, bn1_b, conv2_w, bn2_g, bn2_b,
        proj_w1, proj_b1, proj_w2, proj_b2, q_weights,
        head_w1, head_b1, head_bn_g, head_bn_b, head_w2, head_b2,
        (float*)d_out);
}

// Round 8
// 255.675 us; speedup vs baseline: 5.6363x; 1.0392x over previous
//
#include <hip/hip_runtime.h>
#include <math.h>

// Problem constants (fixed by reference setup_inputs)
#define L0   4448   // flux length
#define L1P  278    // after conv1(stride4,pad7)->1112 then maxpool4
#define L2   139    // after conv2(stride2,pad3) on 278
#define NQ   8
#define NL   3
#define SD   256

// LDS element/word map (float S[7796] = 31184 B):
//  fxb  bf16[4496]      el 0..4495      flux[x] at el x+8; el 0..7 & 4456..4495 zero
//  h1T  bf16[286][20]   el 4496..10215  row = pooled pos + 4; rows 0..3, 282..285 zero
//  Wb   bf16[32][136]   el 10216..14567 conv2 weights, K' = k*16+ic, k=7 row zero
//  Wc1  bf16[16][32]    el 14568..15079 conv1 weights (sign-flipped), K'=1..15 taps
//  featU f32[256]       words 7540..7795 (pool sums; s_U after proj1 — R4 invariant)
// Aliases into dead fxb after stage1: s_hidden w0..63, s_red w64..95, s_q w96..103,
//  s_hid2 w104..135, cre w256..511, cim w512..767.
#define H1T_EL 4496
#define WB_EL  10216
#define WC1_EL 14568
#define FTW    7540

typedef __attribute__((ext_vector_type(4))) short short4v;
typedef __attribute__((ext_vector_type(8))) short short8;
typedef __attribute__((ext_vector_type(4))) float f32x4;
union FragU { short8 v; short4v h[2]; };

__device__ __forceinline__ short f2bf(float x) {   // fp32 -> bf16 (RNE)
    unsigned u = __float_as_uint(x);
    u += 0x7FFFu + ((u >> 16) & 1u);
    return (short)(u >> 16);
}

// CNOT-ring permutation (one layer of 8 CNOTs composed). Linear over GF(2).
constexpr int permsrc_c(int x) {
    for (int q = 7; q >= 0; --q) {
        int cb = 7 - q, tb = 7 - ((q + 1) & 7);
        x ^= ((x >> cb) & 1) << tb;
    }
    return x;
}
constexpr int P40 = permsrc_c(0x40);
constexpr int P80 = permsrc_c(0x80);
constexpr int PC0 = permsrc_c(0xC0);

__device__ __forceinline__ int permsrc(int x) {
    #pragma unroll
    for (int q = 7; q >= 0; --q) {
        int cb = 7 - q, tb = 7 - ((q + 1) & 7);
        x ^= ((x >> cb) & 1) << tb;
    }
    return x;
}

// Combined 2-qubit (bits 7 and 6) gate: out = (U0 on bit7)(U1 on bit6) in.
__device__ __forceinline__ void apply2(const float* __restrict__ U0,
                                       const float* __restrict__ U1,
                                       int a7, int a6,
                                       const float vr[4], const float vi[4],
                                       float& re, float& im)
{
    float nr = 0.0f, ni = 0.0f;
    #pragma unroll
    for (int m7 = 0; m7 < 2; ++m7) {
        const float ur0 = U0[(a7 * 2 + (a7 ^ m7)) * 2];
        const float ui0 = U0[(a7 * 2 + (a7 ^ m7)) * 2 + 1];
        #pragma unroll
        for (int m6 = 0; m6 < 2; ++m6) {
            const float ur1 = U1[(a6 * 2 + (a6 ^ m6)) * 2];
            const float ui1 = U1[(a6 * 2 + (a6 ^ m6)) * 2 + 1];
            const float cr = ur0 * ur1 - ui0 * ui1;
            const float ci = ur0 * ui1 + ui0 * ur1;
            const int   id = m7 * 2 + m6;
            nr += cr * vr[id] - ci * vi[id];
            ni += cr * vi[id] + ci * vr[id];
        }
    }
    re = nr; im = ni;
}

__global__ __launch_bounds__(256, 4)
void aec_fused_kernel(const float* __restrict__ flux,
                      const float* __restrict__ scalars,
                      const float* __restrict__ conv1_w,
                      const float* __restrict__ bn1_g, const float* __restrict__ bn1_b,
                      const float* __restrict__ conv2_w,
                      const float* __restrict__ bn2_g, const float* __restrict__ bn2_b,
                      const float* __restrict__ proj_w1, const float* __restrict__ proj_b1,
                      const float* __restrict__ proj_w2, const float* __restrict__ proj_b2,
                      const float* __restrict__ qw,
                      const float* __restrict__ head_w1, const float* __restrict__ head_b1,
                      const float* __restrict__ head_bn_g, const float* __restrict__ head_bn_b,
                      const float* __restrict__ head_w2, const float* __restrict__ head_b2,
                      float* __restrict__ out)
{
    const int b   = blockIdx.x;
    const int tid = threadIdx.x;

    __shared__ __align__(16) float S[7796];

    float* s_hidden = S;
    float* s_red    = S + 64;
    float* s_q      = S + 96;
    float* s_hid2   = S + 104;
    float* s_cre    = S + 256;
    float* s_cim    = S + 512;
    float* featU    = S + FTW;
    float* s_U      = S + FTW;      // gates overwrite featU AFTER proj1 (R4 invariant)

    const float BN_RSQ = 0.9999950000374997f;     // 1/sqrt(1+1e-5)

    // ---------------- stage 0: zeros + weight matrices + flux staging ----------
    featU[tid] = 0.0f;
    if (tid < 4)                    S[tid] = 0.0f;          // fxb el 0..7
    else if (tid < 64)              S[2224 + tid] = 0.0f;   // fxb tail + h1T rows 0..3
    else if (tid < 104)             S[5004 + tid] = 0.0f;   // h1T rows 282..285
    {
        // Wc1[oc][k'] bf16: k'=0 zero, k'=1..15 = sgn*conv1_w[oc][k'-1], 16..31 zero.
        // Sign flip (exact) makes every effective bn1 scale >= 0 so maxpool can
        // run BEFORE the affine (monotone composition).
        const int oc = tid >> 4;
        const int q  = tid & 15;
        const float sgn = (bn1_g[oc] >= 0.0f) ? 1.0f : -1.0f;
        const int k0 = 2 * q, k1 = 2 * q + 1;
        const short e0 = (k0 >= 1 && k0 <= 15) ? f2bf(sgn * conv1_w[oc * 15 + k0 - 1]) : (short)0;
        const short e1 = (k1 <= 15)            ? f2bf(sgn * conv1_w[oc * 15 + k1 - 1]) : (short)0;
        const unsigned pk = (unsigned short)e0 | ((unsigned)(unsigned short)e1 << 16);
        *(unsigned*)((short*)S + WC1_EL + oc * 32 + 2 * q) = pk;
    }
    {
        // Wb[oc][K'=k*16+ic] bf16, row stride 136; k==7 row is the zero pad.
        const int oc = tid >> 3;
        const int k  = tid & 7;
        short tmp[16];
        #pragma unroll
        for (int ic = 0; ic < 16; ++ic)
            tmp[ic] = (k < 7) ? f2bf(conv2_w[oc * 112 + ic * 7 + k]) : (short)0;
        short8 w0, w1;
        #pragma unroll
        for (int e = 0; e < 8; ++e) { w0[e] = tmp[e]; w1[e] = tmp[8 + e]; }
        short8* dst = (short8*)((char*)S + (WB_EL + oc * 136 + k * 16) * 2);
        dst[0] = w0; dst[1] = w1;
    }
    {
        // flux -> bf16 LDS (el x+8), coalesced float4 loads, aligned b64 stores
        const float4* fg = (const float4*)(flux + (size_t)b * L0);
        short* fx = (short*)S;
        for (int t = tid; t < L0 / 4; t += 256) {
            float4 v = fg[t];
            short4v pk;
            pk[0] = f2bf(v.x); pk[1] = f2bf(v.y); pk[2] = f2bf(v.z); pk[3] = f2bf(v.w);
            *(short4v*)(fx + 8 + 4 * t) = pk;
        }
    }
    __syncthreads();

    // ---------------- stage 1: conv1 as MFMA + maxpool4 + bn + relu -> h1T ------
    // C[16 oc][16 j] per tile, j = conv1 output pos (stride 4): B[k'][j] =
    // fxb[4j + k'] (contiguous in k' -> aligned b64 reads). 70 tiles of 16 cols.
    // D layout: col=lane&15 (j), row=g*4+r (oc). Pool groups = lane bits 0..1.
    {
        const int lane = tid & 63;
        const int wid  = tid >> 6;
        const int col  = lane & 15;
        const int g    = lane >> 4;
        const short* fx = (const short*)S;
        const short8 a = *(const short8*)((const short*)S + WC1_EL + col * 32 + g * 8);
        const float4 g4v = *(const float4*)(bn1_g + g * 4);
        const float4 b4v = *(const float4*)(bn1_b + g * 4);
        const float gs[4] = {fabsf(g4v.x) * BN_RSQ, fabsf(g4v.y) * BN_RSQ,
                             fabsf(g4v.z) * BN_RSQ, fabsf(g4v.w) * BN_RSQ};
        const float bs[4] = {b4v.x, b4v.y, b4v.z, b4v.w};
        const int offm = 8 * (g & 1);      // g>=2 mirrors g<2 (A rows 16..31 zero)

        for (int nt = wid; nt < 70; nt += 4) {
            const int j = nt * 16 + col;
            FragU bu;
            bu.h[0] = *(const short4v*)(fx + 4 * j + offm);
            bu.h[1] = *(const short4v*)(fx + 4 * j + offm + 4);
            f32x4 acc = {0.f, 0.f, 0.f, 0.f};
            acc = __builtin_amdgcn_mfma_f32_16x16x32_bf16(a, bu.v, acc, 0, 0, 0);
            // maxpool4 over lane bits 0..1 (raw conv values; scales all >= 0)
            float mx[4];
            #pragma unroll
            for (int r = 0; r < 4; ++r) {
                float m = acc[r];
                m = fmaxf(m, __shfl_xor(m, 1, 64));
                m = fmaxf(m, __shfl_xor(m, 2, 64));
                mx[r] = m;
            }
            if ((col & 3) == 0) {
                const int p = nt * 4 + (col >> 2);
                if (p < L1P) {
                    short4v pk;
                    #pragma unroll
                    for (int r = 0; r < 4; ++r)
                        pk[r] = f2bf(fmaxf(mx[r] * gs[r] + bs[r], 0.0f));
                    *(short4v*)((short*)S + H1T_EL + (4 + p) * 20 + g * 4) = pk;
                }
            }
        }
    }
    __syncthreads();   // h1T complete; featU still pure pool sums

    // ---------------- stage 2: conv2 as MFMA GEMM + bn/relu + fused pool --------
    // (R7-verified) C[32 oc][144 j] = Wb[32][128] x X[128][144], X[K'][j] =
    // h1T[2j+1+k][ic]. OOB rows (j>138) read into Wb region — masked below.
    {
        const int lane = tid & 63;
        const int wid  = tid >> 6;
        const int col  = lane & 15;
        const int g    = (lane >> 4) & 3;
        const short* h1s = (const short*)S + H1T_EL;
        const char*  wbc = (const char*)((const short*)S + WB_EL);

        for (int nt = wid; nt < 9; nt += 4) {
            const int n0 = nt * 16;
            const int j  = n0 + col;
            f32x4 acc0 = {0.f,0.f,0.f,0.f}, acc1 = {0.f,0.f,0.f,0.f};
            #pragma unroll
            for (int kb = 0; kb < 4; ++kb) {
                const int k   = 2 * kb + (g >> 1);
                const int ic0 = (g & 1) * 8;
                const int row = 2 * j + 1 + k;
                FragU bu;
                bu.h[0] = *(const short4v*)(h1s + row * 20 + ic0);
                bu.h[1] = *(const short4v*)(h1s + row * 20 + ic0 + 4);
                const short8 a0 = *(const short8*)(wbc + (col * 136        + kb*32 + g*8) * 2);
                const short8 a1 = *(const short8*)(wbc + ((16 + col) * 136 + kb*32 + g*8) * 2);
                acc0 = __builtin_amdgcn_mfma_f32_16x16x32_bf16(a0, bu.v, acc0, 0, 0, 0);
                acc1 = __builtin_amdgcn_mfma_f32_16x16x32_bf16(a1, bu.v, acc1, 0, 0, 0);
            }
            // fused adaptive-pool epilogue (verified bin logic, reduced over cols)
            const int   bA  = (8 * n0) / 139;
            const int   sB  = (139 * (bA + 1)) >> 3;      // j<=sB -> bA; j>=sB -> bA+1
            const float rcA = (bA == 2 || bA == 5) ? (1.0f/19.0f) : (1.0f/18.0f);
            const float rcB = (bA == 1 || bA == 4) ? (1.0f/19.0f) : (1.0f/18.0f);
            const int   g4  = g * 4;
            #pragma unroll
            for (int half = 0; half < 2; ++half) {
                const int oc0 = half * 16;
                const float4 sc4 = *(const float4*)(bn2_g + oc0 + g4);
                const float4 bt4 = *(const float4*)(bn2_b + oc0 + g4);
                const float scs[4] = {sc4.x, sc4.y, sc4.z, sc4.w};
                const float bts[4] = {bt4.x, bt4.y, bt4.z, bt4.w};
                const f32x4 A = half ? acc1 : acc0;
                #pragma unroll
                for (int r = 0; r < 4; ++r) {
                    float v = fmaxf(A[r] * (scs[r] * BN_RSQ) + bts[r], 0.0f);
                    if (j > 138) v = 0.0f;
                    float va = (j <= sB) ? v * rcA : 0.0f;
                    float vb = (j >= sB) ? v * rcB : 0.0f;
                    va += __shfl_xor(va, 1, 64); va += __shfl_xor(va, 2, 64);
                    va += __shfl_xor(va, 4, 64); va += __shfl_xor(va, 8, 64);
                    vb += __shfl_xor(vb, 1, 64); vb += __shfl_xor(vb, 2, 64);
                    vb += __shfl_xor(vb, 4, 64); vb += __shfl_xor(vb, 8, 64);
                    if (col == 0) {
                        atomicAdd(&featU[(oc0 + g4 + r) * 8 + bA], va);
                        if (bA < 7)
                            atomicAdd(&featU[(oc0 + g4 + r) * 8 + bA + 1], vb);
                    }
                }
            }
        }
    }
    __syncthreads();

    // ---------------- proj1 (256 -> 64), relu ----------------
    {
        const int o = tid >> 2, s = tid & 3;
        const float4* wg = (const float4*)(proj_w1 + 64 * tid);   // == o*256 + s*64
        const float4* xf = (const float4*)(featU + 64 * s);
        float acc = 0.0f;
        #pragma unroll
        for (int t = 0; t < 16; ++t) {
            float4 w4 = wg[t], x4 = xf[t];
            acc += w4.x * x4.x + w4.y * x4.y + w4.z * x4.z + w4.w * x4.w;
        }
        acc += __shfl_down(acc, 2, 64);
        acc += __shfl_down(acc, 1, 64);
        if (s == 0) s_hidden[o] = fmaxf(acc + proj_b1[o], 0.0f);
    }
    __syncthreads();

    // gate matrices into featU (feat consumed — only safe place, R4 invariant);
    // published by the __syncthreads() inside the normalize sequence below.
    if (tid < NL * NQ) {
        float phi = qw[tid * 3 + 0], th = qw[tid * 3 + 1], om = qw[tid * 3 + 2];
        float ch = cosf(0.5f * th), sh = sinf(0.5f * th);
        float a  = 0.5f * (phi + om), bb = 0.5f * (phi - om);
        float ca = cosf(a), sa = sinf(a), cb = cosf(bb), sb = sinf(bb);
        float* U = &s_U[tid * 8];
        U[0] =  ca * ch; U[1] = -sa * ch;   // U00
        U[2] = -cb * sh; U[3] = -sb * sh;   // U01
        U[4] =  cb * sh; U[5] = -sb * sh;   // U10
        U[6] =  ca * ch; U[7] =  sa * ch;   // U11
    }

    // ---------------- proj2 (64 -> 256) + L2 normalize ----------------
    float re, im;
    {
        const float4* wg = (const float4*)(proj_w2 + 64 * tid);
        const float4* hf = (const float4*)s_hidden;
        float acc = proj_b2[tid];
        #pragma unroll
        for (int t = 0; t < 16; ++t) {
            float4 w4 = wg[t], x4 = hf[t];
            acc += w4.x * x4.x + w4.y * x4.y + w4.z * x4.z + w4.w * x4.w;
        }
        float ss = acc * acc;
        #pragma unroll
        for (int off = 32; off >= 1; off >>= 1) ss += __shfl_xor(ss, off, 64);
        if ((tid & 63) == 0) s_red[tid >> 6] = ss;
        __syncthreads();                           // also publishes s_U
        float sst = s_red[0] + s_red[1] + s_red[2] + s_red[3];
        float n   = sqrtf(sst);
        float inv = 1.0f / fmaxf(n, 1e-12f);
        float xi  = acc * inv;
        if (n * inv < 1e-8f) xi = 0.0625f;        // uniform 1/sqrt(256)
        re = xi; im = 0.0f;
    }

    // ---------------- quantum circuit ----------------
    const int a7 = (tid >> 7) & 1, a6 = (tid >> 6) & 1;
    const int sP = permsrc(tid);

    s_cre[tid] = re; s_cim[tid] = im;
    __syncthreads();
    {
        float vr[4], vi[4];
        vr[0] = re;                vi[0] = im;
        vr[1] = s_cre[tid ^ 0x40]; vi[1] = s_cim[tid ^ 0x40];
        vr[2] = s_cre[tid ^ 0x80]; vi[2] = s_cim[tid ^ 0x80];
        vr[3] = s_cre[tid ^ 0xC0]; vi[3] = s_cim[tid ^ 0xC0];
        __syncthreads();
        apply2(&s_U[0], &s_U[8], a7, a6, vr, vi, re, im);
    }

    #pragma unroll
    for (int l = 0; l < NL; ++l) {
        #pragma unroll
        for (int q = 2; q < NQ; ++q) {
            const float* U = &s_U[(l * NQ + q) * 8];
            const float u00r = U[0], u00i = U[1], u01r = U[2], u01i = U[3];
            const float u10r = U[4], u10i = U[5], u11r = U[6], u11i = U[7];
            const int bp = 7 - q;
            const float pre = __shfl_xor(re, 1 << bp, 64);
            const float pim = __shfl_xor(im, 1 << bp, 64);
            const int bit = (tid >> bp) & 1;
            const float csr = bit ? u11r : u00r;
            const float csi = bit ? u11i : u00i;
            const float cpr = bit ? u10r : u01r;
            const float cpi = bit ? u10i : u01i;
            const float nr = csr * re - csi * im + cpr * pre - cpi * pim;
            const float ni = csr * im + csi * re + cpr * pim + cpi * pre;
            re = nr; im = ni;
        }
        s_cre[tid] = re; s_cim[tid] = im;
        __syncthreads();
        if (l < NL - 1) {
            float vr[4], vi[4];
            vr[0] = s_cre[sP];       vi[0] = s_cim[sP];
            vr[1] = s_cre[sP ^ P40]; vi[1] = s_cim[sP ^ P40];
            vr[2] = s_cre[sP ^ P80]; vi[2] = s_cim[sP ^ P80];
            vr[3] = s_cre[sP ^ PC0]; vi[3] = s_cim[sP ^ PC0];
            __syncthreads();
            apply2(&s_U[((l + 1) * NQ + 0) * 8], &s_U[((l + 1) * NQ + 1) * 8],
                   a7, a6, vr, vi, re, im);
        } else {
            re = s_cre[sP]; im = s_cim[sP];
            __syncthreads();
        }
    }

    // ---------------- Z expectations ----------------
    {
        const float pr = re * re + im * im;
        float zv[8];
        #pragma unroll
        for (int q = 0; q < 8; ++q) zv[q] = ((tid >> (7 - q)) & 1) ? -pr : pr;
        #pragma unroll
        for (int off = 32; off >= 1; off >>= 1) {
            #pragma unroll
            for (int q = 0; q < 8; ++q) zv[q] += __shfl_xor(zv[q], off, 64);
        }
        if ((tid & 63) == 0) {
            const int wid = tid >> 6;
            #pragma unroll
            for (int q = 0; q < 8; ++q) s_red[wid * 8 + q] = zv[q];
        }
        __syncthreads();
        if (tid < 8)
            s_q[tid] = s_red[tid] + s_red[8 + tid] + s_red[16 + tid] + s_red[24 + tid];
        __syncthreads();
    }

    // ---------------- head ----------------
    if (tid < 32) {
        float acc = head_b1[tid];
        #pragma unroll
        for (int k = 0; k < 8; ++k) acc += head_w1[tid * 14 + k] * s_q[k];
        #pragma unroll
        for (int k = 0; k < 6; ++k) acc += head_w1[tid * 14 + 8 + k] * scalars[b * 6 + k];
        float h = fmaxf(acc * (head_bn_g[tid] * BN_RSQ) + head_bn_b[tid], 0.0f);
        s_hid2[tid] = h;
    }
    __syncthreads();
    if (tid < 3) {
        float acc = head_b2[tid];
        #pragma unroll
        for (int k = 0; k < 32; ++k) acc += head_w2[tid * 32 + k] * s_hid2[k];
        out[b * 3 + tid] = acc;
    }
}

extern "C" void kernel_launch(void* const* d_in, const int* in_sizes, int n_in,
                              void* d_out, int out_size, void* d_ws, size_t ws_size,
                              hipStream_t stream) {
    const float* flux      = (const float*)d_in[0];
    const float* scalars   = (const float*)d_in[1];
    const float* conv1_w   = (const float*)d_in[2];
    const float* bn1_g     = (const float*)d_in[3];
    const float* bn1_b     = (const float*)d_in[4];
    const float* conv2_w   = (const float*)d_in[5];
    const float* bn2_g     = (const float*)d_in[6];
    const float* bn2_b     = (const float*)d_in[7];
    const float* proj_w1   = (const float*)d_in[8];
    const float* proj_b1   = (const float*)d_in[9];
    const float* proj_w2   = (const float*)d_in[10];
    const float* proj_b2   = (const float*)d_in[11];
    const float* q_weights = (const float*)d_in[12];
    const float* head_w1   = (const float*)d_in[13];
    const float* head_b1   = (const float*)d_in[14];
    const float* head_bn_g = (const float*)d_in[15];
    const float* head_bn_b = (const float*)d_in[16];
    const float* head_w2   = (const float*)d_in[17];
    const float* head_b2   = (const float*)d_in[18];

    const int B = in_sizes[0] / L0;   // 4096

    aec_fused_kernel<<<dim3(B), dim3(256), 0, stream>>>(
        flux, scalars, conv1_w, bn1_g, bn1_b, conv2_w, bn2_g, bn2_b,
        proj_w1, proj_b1, proj_w2, proj_b2, q_weights,
        head_w1, head_b1, head_bn_g, head_bn_b, head_w2, head_b2,
        (float*)d_out);
}

// Round 9
// 230.255 us; speedup vs baseline: 6.2585x; 1.1104x over previous
//
#include <hip/hip_runtime.h>
#include <math.h>

// Problem constants (fixed by reference setup_inputs)
#define L0   4448   // flux length
#define L1P  278    // after conv1(stride4,pad7)->1112 then maxpool4
#define L2   139    // after conv2(stride2,pad3) on 278
#define NQ   8
#define NL   3
#define SD   256

// LDS element/word map (float S[7796] = 31184 B):
//  fxb  bf16[4496]      el 0..4495      flux[x] at el x+8; el 0..7 & 4456..4495 zero
//  h1T  bf16[286][20]   el 4496..10215  row = pooled pos + 4; rows 0..3, 282..285 zero
//                       (rows 0..3 zero also serve as fxb overread pad, el<=4507)
//  Wb   bf16[32][136]   el 10216..14567 conv2 weights, K' = k*16+ic, k=7 row zero
//  Wc1  bf16[16][32]    el 14568..15079 conv1 weights (sign-flipped), K'=1..15 taps
//  featU f32[256]       words 7540..7795 (pool sums; s_U after proj1 — R4 invariant)
// Aliases into dead fxb after stage1: s_hidden w0..63, s_red w64..95, s_q w96..103,
//  s_hid2 w104..135, cre w256..511, cim w512..767.
#define H1T_EL 4496
#define WB_EL  10216
#define WC1_EL 14568
#define FTW    7540

typedef __attribute__((ext_vector_type(4))) short short4v;
typedef __attribute__((ext_vector_type(8))) short short8;
typedef __attribute__((ext_vector_type(4))) float f32x4;
union FragU { short8 v; short4v h[2]; };

__device__ __forceinline__ short f2bf(float x) {   // fp32 -> bf16 (RNE)
    unsigned u = __float_as_uint(x);
    u += 0x7FFFu + ((u >> 16) & 1u);
    return (short)(u >> 16);
}

// CNOT-ring permutation (one layer of 8 CNOTs composed). Linear over GF(2).
constexpr int permsrc_c(int x) {
    for (int q = 7; q >= 0; --q) {
        int cb = 7 - q, tb = 7 - ((q + 1) & 7);
        x ^= ((x >> cb) & 1) << tb;
    }
    return x;
}
constexpr int P40 = permsrc_c(0x40);
constexpr int P80 = permsrc_c(0x80);
constexpr int PC0 = permsrc_c(0xC0);

__device__ __forceinline__ int permsrc(int x) {
    #pragma unroll
    for (int q = 7; q >= 0; --q) {
        int cb = 7 - q, tb = 7 - ((q + 1) & 7);
        x ^= ((x >> cb) & 1) << tb;
    }
    return x;
}

// Combined 2-qubit (bits 7 and 6) gate: out = (U0 on bit7)(U1 on bit6) in.
__device__ __forceinline__ void apply2(const float* __restrict__ U0,
                                       const float* __restrict__ U1,
                                       int a7, int a6,
                                       const float vr[4], const float vi[4],
                                       float& re, float& im)
{
    float nr = 0.0f, ni = 0.0f;
    #pragma unroll
    for (int m7 = 0; m7 < 2; ++m7) {
        const float ur0 = U0[(a7 * 2 + (a7 ^ m7)) * 2];
        const float ui0 = U0[(a7 * 2 + (a7 ^ m7)) * 2 + 1];
        #pragma unroll
        for (int m6 = 0; m6 < 2; ++m6) {
            const float ur1 = U1[(a6 * 2 + (a6 ^ m6)) * 2];
            const float ui1 = U1[(a6 * 2 + (a6 ^ m6)) * 2 + 1];
            const float cr = ur0 * ur1 - ui0 * ui1;
            const float ci = ur0 * ui1 + ui0 * ur1;
            const int   id = m7 * 2 + m6;
            nr += cr * vr[id] - ci * vi[id];
            ni += cr * vi[id] + ci * vr[id];
        }
    }
    re = nr; im = ni;
}

__global__ __launch_bounds__(256, 4)
void aec_fused_kernel(const float* __restrict__ flux,
                      const float* __restrict__ scalars,
                      const float* __restrict__ conv1_w,
                      const float* __restrict__ bn1_g, const float* __restrict__ bn1_b,
                      const float* __restrict__ conv2_w,
                      const float* __restrict__ bn2_g, const float* __restrict__ bn2_b,
                      const float* __restrict__ proj_w1, const float* __restrict__ proj_b1,
                      const float* __restrict__ proj_w2, const float* __restrict__ proj_b2,
                      const float* __restrict__ qw,
                      const float* __restrict__ head_w1, const float* __restrict__ head_b1,
                      const float* __restrict__ head_bn_g, const float* __restrict__ head_bn_b,
                      const float* __restrict__ head_w2, const float* __restrict__ head_b2,
                      float* __restrict__ out)
{
    const int b   = blockIdx.x;
    const int tid = threadIdx.x;

    __shared__ __align__(16) float S[7796];

    float* s_hidden = S;
    float* s_red    = S + 64;
    float* s_q      = S + 96;
    float* s_hid2   = S + 104;
    float* s_cre    = S + 256;
    float* s_cim    = S + 512;
    float* featU    = S + FTW;
    float* s_U      = S + FTW;      // gates overwrite featU AFTER proj1 (R4 invariant)

    const float BN_RSQ = 0.9999950000374997f;     // 1/sqrt(1+1e-5)

    // ---------------- stage 0: zeros + weight matrices + flux staging ----------
    featU[tid] = 0.0f;
    if (tid < 4)                    S[tid] = 0.0f;          // fxb el 0..7
    else if (tid < 64)              S[2224 + tid] = 0.0f;   // fxb tail + h1T rows 0..3
    else if (tid < 104)             S[5004 + tid] = 0.0f;   // h1T rows 282..285
    {
        // Wc1[oc][k'] bf16: k'=0 zero, k'=1..15 = sgn*conv1_w[oc][k'-1], 16..31 zero.
        // Sign flip (exact) makes every effective bn1 scale >= 0 so maxpool can
        // run BEFORE the affine (monotone composition).
        const int oc = tid >> 4;
        const int q  = tid & 15;
        const float sgn = (bn1_g[oc] >= 0.0f) ? 1.0f : -1.0f;
        const int k0 = 2 * q, k1 = 2 * q + 1;
        const short e0 = (k0 >= 1 && k0 <= 15) ? f2bf(sgn * conv1_w[oc * 15 + k0 - 1]) : (short)0;
        const short e1 = (k1 <= 15)            ? f2bf(sgn * conv1_w[oc * 15 + k1 - 1]) : (short)0;
        const unsigned pk = (unsigned short)e0 | ((unsigned)(unsigned short)e1 << 16);
        *(unsigned*)((short*)S + WC1_EL + oc * 32 + 2 * q) = pk;
    }
    {
        // Wb[oc][K'=k*16+ic] bf16, row stride 136; k==7 row is the zero pad.
        const int oc = tid >> 3;
        const int k  = tid & 7;
        short tmp[16];
        #pragma unroll
        for (int ic = 0; ic < 16; ++ic)
            tmp[ic] = (k < 7) ? f2bf(conv2_w[oc * 112 + ic * 7 + k]) : (short)0;
        short8 w0, w1;
        #pragma unroll
        for (int e = 0; e < 8; ++e) { w0[e] = tmp[e]; w1[e] = tmp[8 + e]; }
        short8* dst = (short8*)((char*)S + (WB_EL + oc * 136 + k * 16) * 2);
        dst[0] = w0; dst[1] = w1;
    }
    {
        // flux -> bf16 LDS (el x+8), coalesced float4 loads, aligned b64 stores
        const float4* fg = (const float4*)(flux + (size_t)b * L0);
        short* fx = (short*)S;
        for (int t = tid; t < L0 / 4; t += 256) {
            float4 v = fg[t];
            short4v pk;
            pk[0] = f2bf(v.x); pk[1] = f2bf(v.y); pk[2] = f2bf(v.z); pk[3] = f2bf(v.w);
            *(short4v*)(fx + 8 + 4 * t) = pk;
        }
    }
    __syncthreads();

    // ---------------- stage 1: conv1 as MFMA (transposed D) + pool + bn --------
    // OPERAND SWAP: D[j][oc] = X^T[16 j][32 k'] x Wc1^T[32][16 oc].
    // A-frag (X): A[m=lane&15 -> j_local][k=quad*8+e] = fxb[4*(n0+m)+k]  (2 b64)
    // B-frag (W): B[k][n=lane&15 -> oc] = Wc1[oc][k]                     (1 b128)
    // D: row (j_local) = quad*4+r, col (oc) = lane&15 -> each lane's 4 regs are
    // 4 CONSECUTIVE conv positions = one maxpool group: pool = 3 fmax, 0 shuffles.
    {
        const int lane = tid & 63;
        const int wid  = tid >> 6;
        const int col  = lane & 15;
        const int quad = lane >> 4;
        const short* fx = (const short*)S;
        const short8 wfrag = *(const short8*)((const short*)S + WC1_EL + col * 32 + quad * 8);
        const float gsc = fabsf(bn1_g[col]) * BN_RSQ;
        const float gbt = bn1_b[col];

        for (int nt = wid; nt < 70; nt += 4) {
            const int jl = nt * 16 + col;          // A's m-row = conv position
            FragU xu;
            xu.h[0] = *(const short4v*)(fx + 4 * jl + quad * 8);
            xu.h[1] = *(const short4v*)(fx + 4 * jl + quad * 8 + 4);
            f32x4 acc = {0.f, 0.f, 0.f, 0.f};
            acc = __builtin_amdgcn_mfma_f32_16x16x32_bf16(xu.v, wfrag, acc, 0, 0, 0);
            const float m = fmaxf(fmaxf(acc[0], acc[1]), fmaxf(acc[2], acc[3]));
            const int p = nt * 4 + quad;           // pooled position
            if (p < L1P) {
                *((short*)S + H1T_EL + (4 + p) * 20 + col) =
                    f2bf(fmaxf(m * gsc + gbt, 0.0f));
            }
        }
    }
    __syncthreads();   // h1T complete; featU still pure pool sums

    // ---------------- stage 2: conv2 as MFMA (transposed D) + bn/relu + pool ----
    // OPERAND SWAP: D[j][oc] = X^T[144 j][128] x Wb^T[128][32 oc]. Loads are
    // byte-identical to R8 (A/B fragment lane maps coincide); only the MFMA
    // operand order changes. Epilogue: lane's 4 regs = 4 consecutive j -> bin
    // partials in VALU; reduce over quads = 2 shfl per accumulator (was 4x16).
    {
        const int lane = tid & 63;
        const int wid  = tid >> 6;
        const int col  = lane & 15;
        const int quad = lane >> 4;
        const short* h1s = (const short*)S + H1T_EL;
        const char*  wbc = (const char*)((const short*)S + WB_EL);
        const float sc0 = bn2_g[col] * BN_RSQ,      bt0 = bn2_b[col];
        const float sc1 = bn2_g[col + 16] * BN_RSQ, bt1 = bn2_b[col + 16];

        for (int nt = wid; nt < 9; nt += 4) {
            const int n0 = nt * 16;
            f32x4 acc0 = {0.f,0.f,0.f,0.f}, acc1 = {0.f,0.f,0.f,0.f};
            #pragma unroll
            for (int kb = 0; kb < 4; ++kb) {
                const int k   = 2 * kb + (quad >> 1);
                const int ic0 = (quad & 1) * 8;
                const int row = 2 * (n0 + col) + 1 + k;
                FragU bu;
                bu.h[0] = *(const short4v*)(h1s + row * 20 + ic0);
                bu.h[1] = *(const short4v*)(h1s + row * 20 + ic0 + 4);
                const short8 a0 = *(const short8*)(wbc + (col * 136        + kb*32 + quad*8) * 2);
                const short8 a1 = *(const short8*)(wbc + ((16 + col) * 136 + kb*32 + quad*8) * 2);
                acc0 = __builtin_amdgcn_mfma_f32_16x16x32_bf16(bu.v, a0, acc0, 0, 0, 0);
                acc1 = __builtin_amdgcn_mfma_f32_16x16x32_bf16(bu.v, a1, acc1, 0, 0, 0);
            }
            // fused adaptive-pool epilogue (R7-verified bin logic, now VALU-local)
            const int   bA  = (8 * n0) / 139;
            const int   sB  = (139 * (bA + 1)) >> 3;      // j<=sB -> bA; j>=sB -> bA+1
            const float rcA = (bA == 2 || bA == 5) ? (1.0f/19.0f) : (1.0f/18.0f);
            const float rcB = (bA == 1 || bA == 4) ? (1.0f/19.0f) : (1.0f/18.0f);
            float va0 = 0.f, vb0 = 0.f, va1 = 0.f, vb1 = 0.f;
            #pragma unroll
            for (int r = 0; r < 4; ++r) {
                const int j = n0 + quad * 4 + r;
                float v0 = fmaxf(acc0[r] * sc0 + bt0, 0.0f);
                float v1 = fmaxf(acc1[r] * sc1 + bt1, 0.0f);
                if (j > 138) { v0 = 0.0f; v1 = 0.0f; }
                if (j <= sB) { va0 += v0; va1 += v1; }
                if (j >= sB) { vb0 += v0; vb1 += v1; }
            }
            va0 += __shfl_xor(va0, 16, 64); va0 += __shfl_xor(va0, 32, 64);
            va1 += __shfl_xor(va1, 16, 64); va1 += __shfl_xor(va1, 32, 64);
            vb0 += __shfl_xor(vb0, 16, 64); vb0 += __shfl_xor(vb0, 32, 64);
            vb1 += __shfl_xor(vb1, 16, 64); vb1 += __shfl_xor(vb1, 32, 64);
            if (quad == 0) {
                atomicAdd(&featU[col * 8 + bA],        va0 * rcA);
                atomicAdd(&featU[(col + 16) * 8 + bA], va1 * rcA);
                if (bA < 7) {
                    atomicAdd(&featU[col * 8 + bA + 1],        vb0 * rcB);
                    atomicAdd(&featU[(col + 16) * 8 + bA + 1], vb1 * rcB);
                }
            }
        }
    }
    __syncthreads();

    // ---------------- proj1 (256 -> 64), relu ----------------
    {
        const int o = tid >> 2, s = tid & 3;
        const float4* wg = (const float4*)(proj_w1 + 64 * tid);   // == o*256 + s*64
        const float4* xf = (const float4*)(featU + 64 * s);
        float acc = 0.0f;
        #pragma unroll
        for (int t = 0; t < 16; ++t) {
            float4 w4 = wg[t], x4 = xf[t];
            acc += w4.x * x4.x + w4.y * x4.y + w4.z * x4.z + w4.w * x4.w;
        }
        acc += __shfl_down(acc, 2, 64);
        acc += __shfl_down(acc, 1, 64);
        if (s == 0) s_hidden[o] = fmaxf(acc + proj_b1[o], 0.0f);
    }
    __syncthreads();

    // gate matrices into featU (feat consumed — only safe place, R4 invariant);
    // published by the __syncthreads() inside the normalize sequence below.
    if (tid < NL * NQ) {
        float phi = qw[tid * 3 + 0], th = qw[tid * 3 + 1], om = qw[tid * 3 + 2];
        float ch = cosf(0.5f * th), sh = sinf(0.5f * th);
        float a  = 0.5f * (phi + om), bb = 0.5f * (phi - om);
        float ca = cosf(a), sa = sinf(a), cb = cosf(bb), sb = sinf(bb);
        float* U = &s_U[tid * 8];
        U[0] =  ca * ch; U[1] = -sa * ch;   // U00
        U[2] = -cb * sh; U[3] = -sb * sh;   // U01
        U[4] =  cb * sh; U[5] = -sb * sh;   // U10
        U[6] =  ca * ch; U[7] =  sa * ch;   // U11
    }

    // ---------------- proj2 (64 -> 256) + L2 normalize ----------------
    float re, im;
    {
        const float4* wg = (const float4*)(proj_w2 + 64 * tid);
        const float4* hf = (const float4*)s_hidden;
        float acc = proj_b2[tid];
        #pragma unroll
        for (int t = 0; t < 16; ++t) {
            float4 w4 = wg[t], x4 = hf[t];
            acc += w4.x * x4.x + w4.y * x4.y + w4.z * x4.z + w4.w * x4.w;
        }
        float ss = acc * acc;
        #pragma unroll
        for (int off = 32; off >= 1; off >>= 1) ss += __shfl_xor(ss, off, 64);
        if ((tid & 63) == 0) s_red[tid >> 6] = ss;
        __syncthreads();                           // also publishes s_U
        float sst = s_red[0] + s_red[1] + s_red[2] + s_red[3];
        float n   = sqrtf(sst);
        float inv = 1.0f / fmaxf(n, 1e-12f);
        float xi  = acc * inv;
        if (n * inv < 1e-8f) xi = 0.0625f;        // uniform 1/sqrt(256)
        re = xi; im = 0.0f;
    }

    // ---------------- quantum circuit ----------------
    const int a7 = (tid >> 7) & 1, a6 = (tid >> 6) & 1;
    const int sP = permsrc(tid);

    s_cre[tid] = re; s_cim[tid] = im;
    __syncthreads();
    {
        float vr[4], vi[4];
        vr[0] = re;                vi[0] = im;
        vr[1] = s_cre[tid ^ 0x40]; vi[1] = s_cim[tid ^ 0x40];
        vr[2] = s_cre[tid ^ 0x80]; vi[2] = s_cim[tid ^ 0x80];
        vr[3] = s_cre[tid ^ 0xC0]; vi[3] = s_cim[tid ^ 0xC0];
        __syncthreads();
        apply2(&s_U[0], &s_U[8], a7, a6, vr, vi, re, im);
    }

    #pragma unroll
    for (int l = 0; l < NL; ++l) {
        #pragma unroll
        for (int q = 2; q < NQ; ++q) {
            const float* U = &s_U[(l * NQ + q) * 8];
            const float u00r = U[0], u00i = U[1], u01r = U[2], u01i = U[3];
            const float u10r = U[4], u10i = U[5], u11r = U[6], u11i = U[7];
            const int bp = 7 - q;
            const float pre = __shfl_xor(re, 1 << bp, 64);
            const float pim = __shfl_xor(im, 1 << bp, 64);
            const int bit = (tid >> bp) & 1;
            const float csr = bit ? u11r : u00r;
            const float csi = bit ? u11i : u00i;
            const float cpr = bit ? u10r : u01r;
            const float cpi = bit ? u10i : u01i;
            const float nr = csr * re - csi * im + cpr * pre - cpi * pim;
            const float ni = csr * im + csi * re + cpr * pim + cpi * pre;
            re = nr; im = ni;
        }
        s_cre[tid] = re; s_cim[tid] = im;
        __syncthreads();
        if (l < NL - 1) {
            float vr[4], vi[4];
            vr[0] = s_cre[sP];       vi[0] = s_cim[sP];
            vr[1] = s_cre[sP ^ P40]; vi[1] = s_cim[sP ^ P40];
            vr[2] = s_cre[sP ^ P80]; vi[2] = s_cim[sP ^ P80];
            vr[3] = s_cre[sP ^ PC0]; vi[3] = s_cim[sP ^ PC0];
            __syncthreads();
            apply2(&s_U[((l + 1) * NQ + 0) * 8], &s_U[((l + 1) * NQ + 1) * 8],
                   a7, a6, vr, vi, re, im);
        } else {
            re = s_cre[sP]; im = s_cim[sP];
            __syncthreads();
        }
    }

    // ---------------- Z expectations ----------------
    {
        const float pr = re * re + im * im;
        float zv[8];
        #pragma unroll
        for (int q = 0; q < 8; ++q) zv[q] = ((tid >> (7 - q)) & 1) ? -pr : pr;
        #pragma unroll
        for (int off = 32; off >= 1; off >>= 1) {
            #pragma unroll
            for (int q = 0; q < 8; ++q) zv[q] += __shfl_xor(zv[q], off, 64);
        }
        if ((tid & 63) == 0) {
            const int wid = tid >> 6;
            #pragma unroll
            for (int q = 0; q < 8; ++q) s_red[wid * 8 + q] = zv[q];
        }
        __syncthreads();
        if (tid < 8)
            s_q[tid] = s_red[tid] + s_red[8 + tid] + s_red[16 + tid] + s_red[24 + tid];
        __syncthreads();
    }

    // ---------------- head ----------------
    if (tid < 32) {
        float acc = head_b1[tid];
        #pragma unroll
        for (int k = 0; k < 8; ++k) acc += head_w1[tid * 14 + k] * s_q[k];
        #pragma unroll
        for (int k = 0; k < 6; ++k) acc += head_w1[tid * 14 + 8 + k] * scalars[b * 6 + k];
        float h = fmaxf(acc * (head_bn_g[tid] * BN_RSQ) + head_bn_b[tid], 0.0f);
        s_hid2[tid] = h;
    }
    __syncthreads();
    if (tid < 3) {
        float acc = head_b2[tid];
        #pragma unroll
        for (int k = 0; k < 32; ++k) acc += head_w2[tid * 32 + k] * s_hid2[k];
        out[b * 3 + tid] = acc;
    }
}

extern "C" void kernel_launch(void* const* d_in, const int* in_sizes, int n_in,
                              void* d_out, int out_size, void* d_ws, size_t ws_size,
                              hipStream_t stream) {
    const float* flux      = (const float*)d_in[0];
    const float* scalars   = (const float*)d_in[1];
    const float* conv1_w   = (const float*)d_in[2];
    const float* bn1_g     = (const float*)d_in[3];
    const float* bn1_b     = (const float*)d_in[4];
    const float* conv2_w   = (const float*)d_in[5];
    const float* bn2_g     = (const float*)d_in[6];
    const float* bn2_b     = (const float*)d_in[7];
    const float* proj_w1   = (const float*)d_in[8];
    const float* proj_b1   = (const float*)d_in[9];
    const float* proj_w2   = (const float*)d_in[10];
    const float* proj_b2   = (const float*)d_in[11];
    const float* q_weights = (const float*)d_in[12];
    const float* head_w1   = (const float*)d_in[13];
    const float* head_b1   = (const float*)d_in[14];
    const float* head_bn_g = (const float*)d_in[15];
    const float* head_bn_b = (const float*)d_in[16];
    const float* head_w2   = (const float*)d_in[17];
    const float* head_b2   = (const float*)d_in[18];

    const int B = in_sizes[0] / L0;   // 4096

    aec_fused_kernel<<<dim3(B), dim3(256), 0, stream>>>(
        flux, scalars, conv1_w, bn1_g, bn1_b, conv2_w, bn2_g, bn2_b,
        proj_w1, proj_b1, proj_w2, proj_b2, q_weights,
        head_w1, head_b1, head_bn_g, head_bn_b, head_w2, head_b2,
        (float*)d_out);
}